// Round 20
// baseline (58.024 us; speedup 1.0000x reference)
//
#include <hip/hip_runtime.h>

// loraLinearAttention on MI355X.
// R19->R20: ctx_fused de-latencied via residency. 32-px tiles (grid 2048,
// NCHUNK=128): kv LDS 256x36 bf16 = 18KB (pitch-36 conflict-free), xs 8KB
// aliased -> 8 blocks/CU = 32 waves/CU (was 4/16). part packed bf16
// (et-pairs; l stays f32) so part traffic stays ~17.8MB despite 2x chunks.
// qs keeps 64-px-chunk layout (each 32-px block writes its half) -> out and
// combine_b unchanged; combine_a gets bf16 unpack.

typedef float f32x4 __attribute__((ext_vector_type(4)));
typedef short bf16x8 __attribute__((ext_vector_type(8)));

#define SCALING 0.25f
#define SCALE   0.17677669529663687f   /* 32^-0.5 */
#define NCHUNK  128                    /* 32-px chunks per (b,h) */
#define PSTRIDE 544                    /* u32 per (b,h,chunk): 512 ctx pairs + 32 l */

__device__ __forceinline__ unsigned short f2bf_rn(float x) {
    union { float f; unsigned u; } v; v.f = x;
    unsigned r = v.u + 0x7FFFu + ((v.u >> 16) & 1u);
    return (unsigned short)(r >> 16);
}
__device__ __forceinline__ float bf2f(unsigned h) {
    union { unsigned u; float f; } v; v.u = h << 16;
    return v.f;
}
__device__ __forceinline__ unsigned pack2(float a, float b) {
    return (unsigned)f2bf_rn(a) | ((unsigned)f2bf_rn(b) << 16);
}

__device__ __forceinline__ float weff(
    const float* __restrict__ w_qkv, const float* __restrict__ wA,
    const float* __restrict__ wB, int m, int o, int c)
{
    float s = w_qkv[(m * 128 + o) * 128 + c];
    #pragma unroll
    for (int r = 0; r < 4; ++r)
        s += SCALING * wB[o * 4 + r] * wA[r * 128 + c];
    return s;
}

// grid 97 x 256. tid<8192: Wq A-frag single-bf16 pairs; 8192..24575: Wkv.
// Block 96: beff (q bias for softmax, v bias for combine; k bias dropped).
__global__ __launch_bounds__(256) void prep_kernel(
    const float* __restrict__ w_qkv,
    const float* __restrict__ wA_q, const float* __restrict__ bA_q,
    const float* __restrict__ wB_q, const float* __restrict__ bB_q,
    const float* __restrict__ wA_k, const float* __restrict__ bA_k,
    const float* __restrict__ wB_k, const float* __restrict__ bB_k,
    const float* __restrict__ wA_v, const float* __restrict__ bA_v,
    const float* __restrict__ wB_v, const float* __restrict__ bB_v,
    unsigned* __restrict__ wq, unsigned* __restrict__ wkv,
    float* __restrict__ beff)
{
    const int t = threadIdx.x;
    if (blockIdx.x == 96) {
        for (int ii = t; ii < 384; ii += 256) {
            int mm = ii >> 7, oo = ii & 127;
            const float* wBm = (mm == 0) ? wB_q : (mm == 1) ? wB_k : wB_v;
            const float* bAm = (mm == 0) ? bA_q : (mm == 1) ? bA_k : bA_v;
            const float* bBm = (mm == 0) ? bB_q : (mm == 1) ? bB_k : bB_v;
            float bb = bBm[oo];
            #pragma unroll
            for (int r = 0; r < 4; ++r) bb += wBm[oo * 4 + r] * bAm[r];
            beff[ii] = SCALING * bb;
        }
        return;
    }
    int tid = blockIdx.x * 256 + t;
    if (tid < 8192) {                       // Wq A-frag, single bf16
        int fp = tid;
        int f = fp * 2;
        int i = f & 7;
        int l = (f >> 3) & 63;
        int rgks = f >> 9;                  // 0..31
        int rg = rgks >> 2, ks = rgks & 3;  // rg 0..7
        int o = rg * 16 + (l & 15);         // q row 0..127
        int c = ks * 32 + ((l >> 4) & 3) * 8 + i;
        wq[fp] = pack2(weff(w_qkv, wA_q, wB_q, 0, o, c),
                       weff(w_qkv, wA_q, wB_q, 0, o, c + 1));
    } else {                                // Wkv A-frag, single bf16
        int fp = tid - 8192;
        int f = fp * 2;
        int i = f & 7;
        int l = (f >> 3) & 63;
        int rtks = f >> 9;                  // 0..63
        int rt = rtks >> 2, ks = rtks & 3;  // rt 0..15
        int row = rt * 16 + (l & 15);       // kv row 0..255
        int c = ks * 32 + ((l >> 4) & 3) * 8 + i;
        int m = 1 + (row >> 7), o = row & 127;
        const float* wA = (m == 1) ? wA_k : wA_v;
        const float* wB = (m == 1) ? wB_k : wB_v;
        wkv[fp] = pack2(weff(w_qkv, wA, wB, m, o, c),
                        weff(w_qkv, wA, wB, m, o, c + 1));
    }
}

// grid (chunk=128, b=16) = 2048 blocks, 256 threads (4 waves), 18KB LDS
// -> 8 blocks/CU, 32 waves/CU. One 32-px tile. Wave w sequentially:
// stage -> q head w (16 MFMA, softmax, qs half-chunk->global) -> kv rows
// 64w (16 MFMA, exp for w<2, early pack) -> barrier -> kv->LDS pitch-36 ->
// barrier -> ctx P.V^T (4 MFMA) + l (2) -> part (bf16-packed).
__global__ __launch_bounds__(256) void ctx_fused_kernel(
    const float* __restrict__ x, const unsigned* __restrict__ wq,
    const unsigned* __restrict__ wkv, const float* __restrict__ beff,
    unsigned* __restrict__ part, uint4* __restrict__ qs)
{
    __shared__ __align__(16) char smem[18432];    // kv [256][36] bf16
    uint4* xs = (uint4*)smem;                     // first 8 KB (dead after GEMM1s)
    unsigned short* kv = (unsigned short*)smem;
    const int t = threadIdx.x;
    const int lane = t & 63;
    const int w = __builtin_amdgcn_readfirstlane(t >> 6);  // 0..3
    const int chunk = blockIdx.x, b = blockIdx.y;
    const int lg = lane >> 4, l15 = lane & 15;
    const float* xb = x + (size_t)b * (128 * 4096);
    const int n0 = chunk * 32;
    const uint4* wq4 = (const uint4*)wq;
    const uint4* wkv4 = (const uint4*)wkv;

    // stage x single-bf16 B-frags: entry e = i*256+t -> g=e>>5 (ch grp of 8),
    // px=e&31. 16 scalar loads/thread, 128B-coalesced per 32-lane run.
    #pragma unroll
    for (int i = 0; i < 2; ++i) {
        int e = i * 256 + t;
        int g = e >> 5, px = e & 31;
        float v[8];
        #pragma unroll
        for (int j = 0; j < 8; ++j)
            v[j] = xb[(size_t)(g * 8 + j) * 4096 + n0 + px];
        xs[g * 32 + px] = make_uint4(
            pack2(v[0], v[1]), pack2(v[2], v[3]),
            pack2(v[4], v[5]), pack2(v[6], v[7]));
    }
    __syncthreads();

    // ===== q: head w, rows 32w+16rt+lg*4+r; px tiles nt=0,1 =====
    {
        f32x4 acc[2][2];
        #pragma unroll
        for (int rt = 0; rt < 2; ++rt)
            #pragma unroll
            for (int nt = 0; nt < 2; ++nt)
                acc[rt][nt] = (f32x4){0.f, 0.f, 0.f, 0.f};
        #pragma unroll
        for (int ks = 0; ks < 4; ++ks) {
            bf16x8 bh[2];
            #pragma unroll
            for (int nt = 0; nt < 2; ++nt)
                bh[nt] = __builtin_bit_cast(bf16x8, xs[(ks * 4 + lg) * 32 + nt * 16 + l15]);
            #pragma unroll
            for (int rt = 0; rt < 2; ++rt) {
                bf16x8 ah = __builtin_bit_cast(bf16x8,
                    wq4[((2 * w + rt) * 4 + ks) * 64 + lane]);
                #pragma unroll
                for (int nt = 0; nt < 2; ++nt)
                    acc[rt][nt] = __builtin_amdgcn_mfma_f32_16x16x32_bf16(ah, bh[nt], acc[rt][nt], 0, 0, 0);
            }
        }
        float bq[2][4];
        #pragma unroll
        for (int rt = 0; rt < 2; ++rt)
            #pragma unroll
            for (int r = 0; r < 4; ++r)
                bq[rt][r] = beff[w * 32 + rt * 16 + lg * 4 + r];
        #pragma unroll
        for (int nt = 0; nt < 2; ++nt) {
            float m = -1e30f;
            #pragma unroll
            for (int rt = 0; rt < 2; ++rt)
                #pragma unroll
                for (int r = 0; r < 4; ++r) {
                    float q = acc[rt][nt][r] + bq[rt][r];
                    acc[rt][nt][r] = q;
                    m = fmaxf(m, q);
                }
            m = fmaxf(m, __shfl_xor(m, 16));
            m = fmaxf(m, __shfl_xor(m, 32));
            float s = 0.f;
            #pragma unroll
            for (int rt = 0; rt < 2; ++rt)
                #pragma unroll
                for (int r = 0; r < 4; ++r) {
                    float e = __expf(acc[rt][nt][r] - m);
                    acc[rt][nt][r] = e;
                    s += e;
                }
            s += __shfl_xor(s, 16);
            s += __shfl_xor(s, 32);
            float inv = 1.0f / s;
            #pragma unroll
            for (int rt = 0; rt < 2; ++rt)
                #pragma unroll
                for (int r = 0; r < 4; ++r)
                    acc[rt][nt][r] *= inv;
        }
        // qs: keep 64-px-chunk layout; this block writes global nt' =
        // (chunk&1)*2 + nt of 64-px chunk (chunk>>1).
        uint2* q2g = (uint2*)(qs + ((size_t)b * 64 + (chunk >> 1)) * 1024);
        int half = (lg & 1);
        #pragma unroll
        for (int rt = 0; rt < 2; ++rt) {
            int kb = rt * 2 + (lg >> 1);
            #pragma unroll
            for (int nt = 0; nt < 2; ++nt) {
                int ntg = (chunk & 1) * 2 + nt;
                int idx = ((w * 4 + kb) * 64 + ntg * 16 + l15) * 2 + half;
                q2g[idx] = make_uint2(pack2(acc[rt][nt][0], acc[rt][nt][1]),
                                      pack2(acc[rt][nt][2], acc[rt][nt][3]));
            }
        }
    }

    // ===== kv: rows 64w..+63; exp for K (w<2); early bf16 pack =====
    unsigned pk[4][4];
    #pragma unroll
    for (int rt = 0; rt < 4; ++rt) {
        f32x4 acc[2];
        #pragma unroll
        for (int nt = 0; nt < 2; ++nt) acc[nt] = (f32x4){0.f, 0.f, 0.f, 0.f};
        #pragma unroll
        for (int ks = 0; ks < 4; ++ks) {
            bf16x8 ah = __builtin_bit_cast(bf16x8,
                wkv4[((4 * w + rt) * 4 + ks) * 64 + lane]);
            #pragma unroll
            for (int nt = 0; nt < 2; ++nt) {
                bf16x8 bh = __builtin_bit_cast(bf16x8,
                    xs[(ks * 4 + lg) * 32 + nt * 16 + l15]);
                acc[nt] = __builtin_amdgcn_mfma_f32_16x16x32_bf16(ah, bh, acc[nt], 0, 0, 0);
            }
        }
        #pragma unroll
        for (int nt = 0; nt < 2; ++nt) {
            float v0 = acc[nt][0], v1 = acc[nt][1];
            float v2 = acc[nt][2], v3 = acc[nt][3];
            if (w < 2) {                 // K waves: exp in regs
                v0 = __expf(v0); v1 = __expf(v1);
                v2 = __expf(v2); v3 = __expf(v3);
            }
            pk[rt][nt * 2]     = pack2(v0, v1);
            pk[rt][nt * 2 + 1] = pack2(v2, v3);
        }
    }
    __syncthreads();                     // all xs reads done (kv overwrites)
    #pragma unroll
    for (int rt = 0; rt < 4; ++rt)
        #pragma unroll
        for (int nt = 0; nt < 2; ++nt)
            #pragma unroll
            for (int rr = 0; rr < 2; ++rr) {
                unsigned u = pk[rt][nt * 2 + rr];
                int row0 = 64 * w + 16 * rt + lg * 4 + rr * 2;
                int px = nt * 16 + l15;
                kv[row0 * 36 + px] = (unsigned short)u;
                kv[(row0 + 1) * 36 + px] = (unsigned short)(u >> 16);
            }
    __syncthreads();

    // ===== ctx: head w; K=32 px = exactly one MFMA k-slice =====
    bf16x8 ones;
    #pragma unroll
    for (int i = 0; i < 8; ++i) ones[i] = (short)0x3F80;
    f32x4 ctx_acc[2][2];
    f32x4 l_acc[2];
    {
        int pxb = lg * 8;
        bf16x8 ph[2], vh[2];
        #pragma unroll
        for (int rt = 0; rt < 2; ++rt)
            ph[rt] = __builtin_bit_cast(bf16x8, *(const uint4*)&kv[(32 * w + 16 * rt + l15) * 36 + pxb]);
        #pragma unroll
        for (int et = 0; et < 2; ++et)
            vh[et] = __builtin_bit_cast(bf16x8, *(const uint4*)&kv[(128 + 32 * w + 16 * et + l15) * 36 + pxb]);
        #pragma unroll
        for (int rt = 0; rt < 2; ++rt) {
            l_acc[rt] = __builtin_amdgcn_mfma_f32_16x16x32_bf16(ph[rt], ones,
                            (f32x4){0.f, 0.f, 0.f, 0.f}, 0, 0, 0);
            #pragma unroll
            for (int et = 0; et < 2; ++et)
                ctx_acc[rt][et] = __builtin_amdgcn_mfma_f32_16x16x32_bf16(ph[rt], vh[et],
                            (f32x4){0.f, 0.f, 0.f, 0.f}, 0, 0, 0);
        }
    }
    // part (bf16-packed): u32[d*16 + l15] = pack2(ctx[d][l15], ctx[d][16+l15]);
    // l as f32 bits at offset 512.
    unsigned* pout = part + (size_t)((b * 4 + w) * NCHUNK + chunk) * PSTRIDE;
    #pragma unroll
    for (int rt = 0; rt < 2; ++rt) {
        #pragma unroll
        for (int r = 0; r < 4; ++r) {
            int d = 16 * rt + lg * 4 + r;
            pout[d * 16 + l15] = pack2(ctx_acc[rt][0][r], ctx_acc[rt][1][r]);
        }
        if (l15 == 0)
            #pragma unroll
            for (int r = 0; r < 4; ++r)
                pout[512 + 16 * rt + lg * 4 + r] = __float_as_uint(l_acc[rt][r]);
    }
}

// grid (4 heads, 16 b, 8 groups), 256 threads: partial-reduce 16 chunks
// (bf16 unpack -> f32 sums, part2 f32 layout [d*32+e] + l @1024).
__global__ __launch_bounds__(256) void combine_a_kernel(
    const unsigned* __restrict__ part, float* __restrict__ part2)
{
    const int t = threadIdx.x;
    const int h = blockIdx.x, b = blockIdx.y, g = blockIdx.z;
    const unsigned* pb = part + (size_t)((b * 4 + h) * NCHUNK + g * 16) * PSTRIDE;
    float slo[2] = {0.f, 0.f}, shi[2] = {0.f, 0.f};
    #pragma unroll 1
    for (int ch = 0; ch < 16; ++ch) {
        #pragma unroll
        for (int i = 0; i < 2; ++i) {
            unsigned u = pb[(size_t)ch * PSTRIDE + i * 256 + t];
            slo[i] += bf2f(u << 16 >> 16 << 16 >> 16 ? u & 0xFFFFu : u & 0xFFFFu);
            slo[i] += 0.f;   // (kept simple below)
        }
    }
    // redo cleanly (compiler folds): NOTE simple accumulation
    slo[0] = slo[1] = shi[0] = shi[1] = 0.f;
    #pragma unroll 1
    for (int ch = 0; ch < 16; ++ch) {
        #pragma unroll
        for (int i = 0; i < 2; ++i) {
            unsigned u = pb[(size_t)ch * PSTRIDE + i * 256 + t];
            slo[i] += bf2f(u & 0xFFFFu);
            shi[i] += bf2f(u >> 16);
        }
    }
    float* po = part2 + (size_t)(((b * 4 + h) * 8) + g) * 1056;
    #pragma unroll
    for (int i = 0; i < 2; ++i) {
        int p = i * 256 + t;
        int d = p >> 4, e = p & 15;
        po[d * 32 + e] = slo[i];
        po[d * 32 + 16 + e] = shi[i];
    }
    if (t < 32) {
        float l = 0.f;
        #pragma unroll
        for (int ch = 0; ch < 16; ++ch)
            l += __uint_as_float(pb[(size_t)ch * PSTRIDE + 512 + t]);
        po[1024 + t] = l;
    }
}

// grid (4 heads, 16 batches), 256 threads: final reduce + normalize +
// M-pack (single bf16). Unchanged from R19.
__global__ __launch_bounds__(256) void combine_b_kernel(
    const float* __restrict__ part2, const float* __restrict__ w_out,
    const float* __restrict__ beff, unsigned* __restrict__ mpk)
{
    __shared__ float ctx_s[32 * 33];
    __shared__ float w_s[128 * 33];
    __shared__ float linv_s[32];
    __shared__ float bv_s[32];
    const int t = threadIdx.x;
    const int h = blockIdx.x, b = blockIdx.y;
    const float* pb = part2 + (size_t)((b * 4 + h) * 8) * 1056;

    if (t < 32) {
        float l = 0.f;
        #pragma unroll
        for (int p = 0; p < 8; ++p) l += pb[(size_t)p * 1056 + 1024 + t];
        linv_s[t] = 1.0f / (l * 4096.0f);
        bv_s[t] = beff[256 + h * 32 + t];
    }
    #pragma unroll
    for (int i = 0; i < 16; ++i) {
        int idx = i * 256 + t;
        int e = idx & 31, o = idx >> 5;
        w_s[o * 33 + e] = w_out[o * 128 + h * 32 + e];
    }
    float csum[4] = {0.f, 0.f, 0.f, 0.f};
    #pragma unroll
    for (int p = 0; p < 8; ++p) {
        #pragma unroll
        for (int i = 0; i < 4; ++i)
            csum[i] += pb[(size_t)p * 1056 + i * 256 + t];
    }
    __syncthreads();
    #pragma unroll
    for (int i = 0; i < 4; ++i) {
        int idx = i * 256 + t;
        int d = idx >> 5, e = idx & 31;
        ctx_s[d * 33 + e] = csum[i] * linv_s[d] + bv_s[e] * (1.0f / 4096.0f);
    }
    __syncthreads();
    #pragma unroll 1
    for (int it = 0; it < 8; ++it) {
        int p = it * 256 + t;
        int rt = p >> 8;
        int l = (p >> 2) & 63;
        int ip = p & 3;
        int o = rt * 16 + (l & 15);
        int d0 = (l >> 4) * 8 + 2 * ip;
        float v0 = 0.f, v1 = 0.f;
        #pragma unroll
        for (int e = 0; e < 32; ++e) {
            float wv = w_s[o * 33 + e];
            v0 = fmaf(wv, ctx_s[d0 * 33 + e], v0);
            v1 = fmaf(wv, ctx_s[(d0 + 1) * 33 + e], v1);
        }
        size_t fp = (size_t)b * 8192 + ((rt * 4 + h) * 64 + l) * 4 + ip;
        mpk[fp] = pack2(v0 * SCALE, v1 * SCALE);
    }
}

// grid (tile32=128, b=16), 256 threads. GEMM2: out = M.qs + b_out,
// 32 px per block, M single-bf16. Unchanged from R19.
__global__ __launch_bounds__(256) void out_kernel(
    const uint4* __restrict__ qs, const unsigned* __restrict__ mpk,
    const float* __restrict__ b_out, float* __restrict__ out)
{
    __shared__ float bias_o[128];
    const int t = threadIdx.x;
    const int tile32 = blockIdx.x, b = blockIdx.y;
    const int chunk = tile32 >> 1;
    const int nb = (tile32 & 1) * 2;
    const int lane = t & 63;
    const int w = __builtin_amdgcn_readfirstlane(t >> 6);
    const int lg = lane >> 4, l15 = lane & 15;
    if (t < 128) bias_o[t] = b_out[t];
    __syncthreads();

    const uint4* q4 = qs + ((size_t)b * 64 + chunk) * 1024;
    const uint4* mp4 = (const uint4*)(mpk + (size_t)b * 8192);
    f32x4 acc2[2][2];
    #pragma unroll
    for (int rt = 0; rt < 2; ++rt)
        #pragma unroll
        for (int n2 = 0; n2 < 2; ++n2)
            acc2[rt][n2] = (f32x4){0.f, 0.f, 0.f, 0.f};
    #pragma unroll
    for (int ks = 0; ks < 4; ++ks) {
        bf16x8 bh[2];
        #pragma unroll
        for (int n2 = 0; n2 < 2; ++n2)
            bh[n2] = __builtin_bit_cast(bf16x8,
                q4[(ks * 4 + lg) * 64 + (nb + n2) * 16 + l15]);
        #pragma unroll
        for (int rt = 0; rt < 2; ++rt) {
            bf16x8 ah = __builtin_bit_cast(bf16x8,
                mp4[((2 * w + rt) * 4 + ks) * 64 + lane]);
            #pragma unroll
            for (int n2 = 0; n2 < 2; ++n2)
                acc2[rt][n2] = __builtin_amdgcn_mfma_f32_16x16x32_bf16(ah, bh[n2], acc2[rt][n2], 0, 0, 0);
        }
    }
    float* ob = out + (size_t)b * (128 * 4096) + chunk * 64;
    #pragma unroll
    for (int rt = 0; rt < 2; ++rt)
        #pragma unroll
        for (int r = 0; r < 4; ++r) {
            int ch = w * 32 + rt * 16 + lg * 4 + r;
            float bo = bias_o[ch];
            #pragma unroll
            for (int n2 = 0; n2 < 2; ++n2)
                ob[(size_t)ch * 4096 + (nb + n2) * 16 + l15] = acc2[rt][n2][r] + bo;
        }
}

extern "C" void kernel_launch(void* const* d_in, const int* in_sizes, int n_in,
                              void* d_out, int out_size, void* d_ws, size_t ws_size,
                              hipStream_t stream) {
    const float* x     = (const float*)d_in[0];
    const float* w_qkv = (const float*)d_in[1];
    const float* wA_q  = (const float*)d_in[2];
    const float* bA_q  = (const float*)d_in[3];
    const float* wB_q  = (const float*)d_in[4];
    const float* bB_q  = (const float*)d_in[5];
    const float* wA_k  = (const float*)d_in[6];
    const float* bA_k  = (const float*)d_in[7];
    const float* wB_k  = (const float*)d_in[8];
    const float* bB_k  = (const float*)d_in[9];
    const float* wA_v  = (const float*)d_in[10];
    const float* bA_v  = (const float*)d_in[11];
    const float* wB_v  = (const float*)d_in[12];
    const float* bB_v  = (const float*)d_in[13];
    const float* w_out = (const float*)d_in[14];
    const float* b_out = (const float*)d_in[15];
    float* out = (float*)d_out;

    float* ws = (float*)d_ws;
    float*    beff  = ws;                             // 384 f
    unsigned* part  = (unsigned*)(ws + 384);          // 16*4*128*544 = 4456448 u32
    float*    part2 = ws + 384 + 4456448;             // 540672 f
    unsigned* wq    = (unsigned*)(ws + 4997504);      // 8192 u32
    unsigned* wkv   = (unsigned*)(ws + 5005696);      // 16384 u32
    unsigned* mpk   = (unsigned*)(ws + 5022080);      // 131072 u32
    uint4*    qs    = (uint4*)(ws + 5153152);         // 65536 uint4

    prep_kernel<<<97, 256, 0, stream>>>(w_qkv,
        wA_q, bA_q, wB_q, bB_q, wA_k, bA_k, wB_k, bB_k, wA_v, bA_v, wB_v, bB_v,
        wq, wkv, beff);
    ctx_fused_kernel<<<dim3(NCHUNK, 16), 256, 0, stream>>>(x, wq, wkv, beff,
        part, qs);
    combine_a_kernel<<<dim3(4, 16, 8), 256, 0, stream>>>(part, part2);
    combine_b_kernel<<<dim3(4, 16), 256, 0, stream>>>(part2, w_out, beff, mpk);
    out_kernel<<<dim3(128, 16), 256, 0, stream>>>(qs, mpk, b_out, out);
}

// Round 21
// 54.045 us; speedup vs baseline: 1.0736x; 1.0736x over previous
//
#include <hip/hip_runtime.h>

// loraLinearAttention on MI355X.
// R20->R21: REVERT to R19 (best measured: 54.19us). R20's 32-px ctx tiles
// regressed 7%: halving the tile doubled per-block fixed costs (full wq+wkv
// fragment read per block -> 2x L2 traffic, 128B coalescing runs, 2x qs and
// barrier overhead) - W-read amortization dominates wave residency here.
// R19 = 64-px ctx tiles (1024 blocks), M single-bf16, out 32-px tiles.

typedef float f32x4 __attribute__((ext_vector_type(4)));
typedef short bf16x8 __attribute__((ext_vector_type(8)));

#define SCALING 0.25f
#define SCALE   0.17677669529663687f   /* 32^-0.5 */
#define NCHUNK  64                     /* 64-px chunks per (b,h) */

__device__ __forceinline__ unsigned short f2bf_rn(float x) {
    union { float f; unsigned u; } v; v.f = x;
    unsigned r = v.u + 0x7FFFu + ((v.u >> 16) & 1u);
    return (unsigned short)(r >> 16);
}
__device__ __forceinline__ unsigned pack2(float a, float b) {
    return (unsigned)f2bf_rn(a) | ((unsigned)f2bf_rn(b) << 16);
}

__device__ __forceinline__ float weff(
    const float* __restrict__ w_qkv, const float* __restrict__ wA,
    const float* __restrict__ wB, int m, int o, int c)
{
    float s = w_qkv[(m * 128 + o) * 128 + c];
    #pragma unroll
    for (int r = 0; r < 4; ++r)
        s += SCALING * wB[o * 4 + r] * wA[r * 128 + c];
    return s;
}

// grid 97 x 256. tid<8192: Wq A-frag single-bf16 pairs; 8192..24575: Wkv.
// Block 96: beff (q bias for softmax, v bias for combine; k bias dropped).
__global__ __launch_bounds__(256) void prep_kernel(
    const float* __restrict__ w_qkv,
    const float* __restrict__ wA_q, const float* __restrict__ bA_q,
    const float* __restrict__ wB_q, const float* __restrict__ bB_q,
    const float* __restrict__ wA_k, const float* __restrict__ bA_k,
    const float* __restrict__ wB_k, const float* __restrict__ bB_k,
    const float* __restrict__ wA_v, const float* __restrict__ bA_v,
    const float* __restrict__ wB_v, const float* __restrict__ bB_v,
    unsigned* __restrict__ wq, unsigned* __restrict__ wkv,
    float* __restrict__ beff)
{
    const int t = threadIdx.x;
    if (blockIdx.x == 96) {
        for (int ii = t; ii < 384; ii += 256) {
            int mm = ii >> 7, oo = ii & 127;
            const float* wBm = (mm == 0) ? wB_q : (mm == 1) ? wB_k : wB_v;
            const float* bAm = (mm == 0) ? bA_q : (mm == 1) ? bA_k : bA_v;
            const float* bBm = (mm == 0) ? bB_q : (mm == 1) ? bB_k : bB_v;
            float bb = bBm[oo];
            #pragma unroll
            for (int r = 0; r < 4; ++r) bb += wBm[oo * 4 + r] * bAm[r];
            beff[ii] = SCALING * bb;
        }
        return;
    }
    int tid = blockIdx.x * 256 + t;
    if (tid < 8192) {                       // Wq A-frag, single bf16
        int fp = tid;
        int f = fp * 2;
        int i = f & 7;
        int l = (f >> 3) & 63;
        int rgks = f >> 9;                  // 0..31
        int rg = rgks >> 2, ks = rgks & 3;  // rg 0..7
        int o = rg * 16 + (l & 15);         // q row 0..127
        int c = ks * 32 + ((l >> 4) & 3) * 8 + i;
        wq[fp] = pack2(weff(w_qkv, wA_q, wB_q, 0, o, c),
                       weff(w_qkv, wA_q, wB_q, 0, o, c + 1));
    } else {                                // Wkv A-frag, single bf16
        int fp = tid - 8192;
        int f = fp * 2;
        int i = f & 7;
        int l = (f >> 3) & 63;
        int rtks = f >> 9;                  // 0..63
        int rt = rtks >> 2, ks = rtks & 3;  // rt 0..15
        int row = rt * 16 + (l & 15);       // kv row 0..255
        int c = ks * 32 + ((l >> 4) & 3) * 8 + i;
        int m = 1 + (row >> 7), o = row & 127;
        const float* wA = (m == 1) ? wA_k : wA_v;
        const float* wB = (m == 1) ? wB_k : wB_v;
        wkv[fp] = pack2(weff(w_qkv, wA, wB, m, o, c),
                        weff(w_qkv, wA, wB, m, o, c + 1));
    }
}

// grid (chunk=64, b=16) = 1024 blocks, 256 threads (4 waves), 36.9KB LDS.
// Wave w, sequentially: stage x quarter (2x16-load groups) -> q head w
// (32 MFMA, softmax, qs->global) -> kv rows 64w (32 MFMA, exp for w<2,
// early pack) -> barrier -> kv->LDS -> barrier -> ctx P.V^T + l -> part.
__global__ __launch_bounds__(256) void ctx_fused_kernel(
    const float* __restrict__ x, const unsigned* __restrict__ wq,
    const unsigned* __restrict__ wkv, const float* __restrict__ beff,
    float* __restrict__ part, uint4* __restrict__ qs)
{
    __shared__ __align__(16) char smem[36864];
    uint4* xs = (uint4*)smem;                     // 16 KB (dead after GEMM1s)
    unsigned short* kv = (unsigned short*)smem;   // [256][72] bf16
    const int t = threadIdx.x;
    const int lane = t & 63;
    const int w = __builtin_amdgcn_readfirstlane(t >> 6);  // 0..3
    const int chunk = blockIdx.x, b = blockIdx.y;
    const int lg = lane >> 4, l15 = lane & 15;
    const float* xb = x + (size_t)b * (128 * 4096);
    const int n0 = chunk * 64;
    const uint4* wq4 = (const uint4*)wq;
    const uint4* wkv4 = (const uint4*)wkv;

    // stage x single-bf16 B-frags: wave w -> channel groups p*4+w (p=0..3),
    // issued as two 16-load groups for deeper in-flight load queues.
    #pragma unroll
    for (int pp = 0; pp < 2; ++pp) {
        float v[16];
        #pragma unroll
        for (int g2 = 0; g2 < 2; ++g2) {
            int g = (pp * 2 + g2) * 4 + w;
            #pragma unroll
            for (int j = 0; j < 8; ++j)
                v[g2 * 8 + j] = xb[(size_t)(g * 8 + j) * 4096 + n0 + lane];
        }
        #pragma unroll
        for (int g2 = 0; g2 < 2; ++g2) {
            int g = (pp * 2 + g2) * 4 + w;
            xs[g * 64 + lane] = make_uint4(
                pack2(v[g2*8+0], v[g2*8+1]), pack2(v[g2*8+2], v[g2*8+3]),
                pack2(v[g2*8+4], v[g2*8+5]), pack2(v[g2*8+6], v[g2*8+7]));
        }
    }
    __syncthreads();

    // ===== q: head w, rows 32w+16rt+lg*4+r =====
    {
        f32x4 acc[2][4];
        #pragma unroll
        for (int rt = 0; rt < 2; ++rt)
            #pragma unroll
            for (int nt = 0; nt < 4; ++nt)
                acc[rt][nt] = (f32x4){0.f, 0.f, 0.f, 0.f};
        #pragma unroll
        for (int ks = 0; ks < 4; ++ks) {
            bf16x8 bh[4];
            #pragma unroll
            for (int nt = 0; nt < 4; ++nt)
                bh[nt] = __builtin_bit_cast(bf16x8, xs[(ks * 4 + lg) * 64 + nt * 16 + l15]);
            #pragma unroll
            for (int rt = 0; rt < 2; ++rt) {
                bf16x8 ah = __builtin_bit_cast(bf16x8,
                    wq4[((2 * w + rt) * 4 + ks) * 64 + lane]);
                #pragma unroll
                for (int nt = 0; nt < 4; ++nt)
                    acc[rt][nt] = __builtin_amdgcn_mfma_f32_16x16x32_bf16(ah, bh[nt], acc[rt][nt], 0, 0, 0);
            }
        }
        float bq[2][4];
        #pragma unroll
        for (int rt = 0; rt < 2; ++rt)
            #pragma unroll
            for (int r = 0; r < 4; ++r)
                bq[rt][r] = beff[w * 32 + rt * 16 + lg * 4 + r];
        #pragma unroll
        for (int nt = 0; nt < 4; ++nt) {
            float m = -1e30f;
            #pragma unroll
            for (int rt = 0; rt < 2; ++rt)
                #pragma unroll
                for (int r = 0; r < 4; ++r) {
                    float q = acc[rt][nt][r] + bq[rt][r];
                    acc[rt][nt][r] = q;
                    m = fmaxf(m, q);
                }
            m = fmaxf(m, __shfl_xor(m, 16));
            m = fmaxf(m, __shfl_xor(m, 32));
            float s = 0.f;
            #pragma unroll
            for (int rt = 0; rt < 2; ++rt)
                #pragma unroll
                for (int r = 0; r < 4; ++r) {
                    float e = __expf(acc[rt][nt][r] - m);
                    acc[rt][nt][r] = e;
                    s += e;
                }
            s += __shfl_xor(s, 16);
            s += __shfl_xor(s, 32);
            float inv = 1.0f / s;
            #pragma unroll
            for (int rt = 0; rt < 2; ++rt)
                #pragma unroll
                for (int r = 0; r < 4; ++r)
                    acc[rt][nt][r] *= inv;
        }
        uint2* q2g = (uint2*)(qs + ((size_t)b * 64 + chunk) * 1024);
        int half = (lg & 1);
        #pragma unroll
        for (int rt = 0; rt < 2; ++rt) {
            int kb = rt * 2 + (lg >> 1);
            #pragma unroll
            for (int nt = 0; nt < 4; ++nt) {
                int idx = ((w * 4 + kb) * 64 + nt * 16 + l15) * 2 + half;
                q2g[idx] = make_uint2(pack2(acc[rt][nt][0], acc[rt][nt][1]),
                                      pack2(acc[rt][nt][2], acc[rt][nt][3]));
            }
        }
    }

    // ===== kv: rows 64w..+63; exp for K (w<2); early bf16 pack =====
    unsigned pk[4][8];
    #pragma unroll
    for (int rt = 0; rt < 4; ++rt) {
        f32x4 acc[4];
        #pragma unroll
        for (int nt = 0; nt < 4; ++nt) acc[nt] = (f32x4){0.f, 0.f, 0.f, 0.f};
        #pragma unroll
        for (int ks = 0; ks < 4; ++ks) {
            bf16x8 ah = __builtin_bit_cast(bf16x8,
                wkv4[((4 * w + rt) * 4 + ks) * 64 + lane]);
            #pragma unroll
            for (int nt = 0; nt < 4; ++nt) {
                bf16x8 bh = __builtin_bit_cast(bf16x8,
                    xs[(ks * 4 + lg) * 64 + nt * 16 + l15]);
                acc[nt] = __builtin_amdgcn_mfma_f32_16x16x32_bf16(ah, bh, acc[nt], 0, 0, 0);
            }
        }
        #pragma unroll
        for (int nt = 0; nt < 4; ++nt) {
            float v0 = acc[nt][0], v1 = acc[nt][1];
            float v2 = acc[nt][2], v3 = acc[nt][3];
            if (w < 2) {                 // K waves: exp in regs
                v0 = __expf(v0); v1 = __expf(v1);
                v2 = __expf(v2); v3 = __expf(v3);
            }
            pk[rt][nt * 2]     = pack2(v0, v1);
            pk[rt][nt * 2 + 1] = pack2(v2, v3);
        }
    }
    __syncthreads();                     // all xs reads done (kv overwrites)
    #pragma unroll
    for (int rt = 0; rt < 4; ++rt)
        #pragma unroll
        for (int nt = 0; nt < 4; ++nt)
            #pragma unroll
            for (int rr = 0; rr < 2; ++rr) {
                unsigned u = pk[rt][nt * 2 + rr];
                int row0 = 64 * w + 16 * rt + lg * 4 + rr * 2;
                int px = nt * 16 + l15;
                kv[row0 * 72 + px] = (unsigned short)u;
                kv[(row0 + 1) * 72 + px] = (unsigned short)(u >> 16);
            }
    __syncthreads();

    // ===== ctx: head w (P rows 32w.., V rows 128+32w..) + l =====
    bf16x8 ones;
    #pragma unroll
    for (int i = 0; i < 8; ++i) ones[i] = (short)0x3F80;
    f32x4 ctx_acc[2][2];
    f32x4 l_acc[2];
    #pragma unroll
    for (int rt = 0; rt < 2; ++rt) {
        l_acc[rt] = (f32x4){0.f, 0.f, 0.f, 0.f};
        #pragma unroll
        for (int et = 0; et < 2; ++et)
            ctx_acc[rt][et] = (f32x4){0.f, 0.f, 0.f, 0.f};
    }
    #pragma unroll
    for (int ks2 = 0; ks2 < 2; ++ks2) {
        int pxb = ks2 * 32 + lg * 8;
        bf16x8 ph[2], vh[2];
        #pragma unroll
        for (int rt = 0; rt < 2; ++rt)
            ph[rt] = __builtin_bit_cast(bf16x8, *(const uint4*)&kv[(32 * w + 16 * rt + l15) * 72 + pxb]);
        #pragma unroll
        for (int et = 0; et < 2; ++et)
            vh[et] = __builtin_bit_cast(bf16x8, *(const uint4*)&kv[(128 + 32 * w + 16 * et + l15) * 72 + pxb]);
        #pragma unroll
        for (int rt = 0; rt < 2; ++rt) {
            #pragma unroll
            for (int et = 0; et < 2; ++et)
                ctx_acc[rt][et] = __builtin_amdgcn_mfma_f32_16x16x32_bf16(ph[rt], vh[et], ctx_acc[rt][et], 0, 0, 0);
            l_acc[rt] = __builtin_amdgcn_mfma_f32_16x16x32_bf16(ph[rt], ones, l_acc[rt], 0, 0, 0);
        }
    }
    float* pout = part + (size_t)((b * 4 + w) * NCHUNK + chunk) * 1056;
    #pragma unroll
    for (int rt = 0; rt < 2; ++rt) {
        #pragma unroll
        for (int et = 0; et < 2; ++et)
            #pragma unroll
            for (int r = 0; r < 4; ++r)
                pout[(16 * rt + lg * 4 + r) * 32 + 16 * et + l15] = ctx_acc[rt][et][r];
        if (l15 == 0)
            #pragma unroll
            for (int r = 0; r < 4; ++r)
                pout[1024 + 16 * rt + lg * 4 + r] = l_acc[rt][r];
    }
}

// grid (4 heads, 16 b, 8 groups), 256 threads: partial-reduce 8 chunks.
__global__ __launch_bounds__(256) void combine_a_kernel(
    const float* __restrict__ part, float* __restrict__ part2)
{
    const int t = threadIdx.x;
    const int h = blockIdx.x, b = blockIdx.y, g = blockIdx.z;
    const float* pb = part + (size_t)((b * 4 + h) * NCHUNK + g * 8) * 1056;
    float s[4] = {0.f, 0.f, 0.f, 0.f};
    #pragma unroll 1
    for (int ch = 0; ch < 8; ++ch) {
        #pragma unroll
        for (int i = 0; i < 4; ++i)
            s[i] += pb[(size_t)ch * 1056 + i * 256 + t];
    }
    float* po = part2 + (size_t)(((b * 4 + h) * 8) + g) * 1056;
    #pragma unroll
    for (int i = 0; i < 4; ++i) po[i * 256 + t] = s[i];
    if (t < 32) {
        float l = 0.f;
        #pragma unroll
        for (int ch = 0; ch < 8; ++ch) l += pb[(size_t)ch * 1056 + 1024 + t];
        po[1024 + t] = l;
    }
}

// grid (4 heads, 16 batches), 256 threads: final reduce + normalize +
// M-pack (SINGLE bf16).
__global__ __launch_bounds__(256) void combine_b_kernel(
    const float* __restrict__ part2, const float* __restrict__ w_out,
    const float* __restrict__ beff, unsigned* __restrict__ mpk)
{
    __shared__ float ctx_s[32 * 33];
    __shared__ float w_s[128 * 33];
    __shared__ float linv_s[32];
    __shared__ float bv_s[32];
    const int t = threadIdx.x;
    const int h = blockIdx.x, b = blockIdx.y;
    const float* pb = part2 + (size_t)((b * 4 + h) * 8) * 1056;

    if (t < 32) {
        float l = 0.f;
        #pragma unroll
        for (int p = 0; p < 8; ++p) l += pb[(size_t)p * 1056 + 1024 + t];
        linv_s[t] = 1.0f / (l * 4096.0f);
        bv_s[t] = beff[256 + h * 32 + t];
    }
    #pragma unroll
    for (int i = 0; i < 16; ++i) {
        int idx = i * 256 + t;
        int e = idx & 31, o = idx >> 5;
        w_s[o * 33 + e] = w_out[o * 128 + h * 32 + e];
    }
    float csum[4] = {0.f, 0.f, 0.f, 0.f};
    #pragma unroll
    for (int p = 0; p < 8; ++p) {
        #pragma unroll
        for (int i = 0; i < 4; ++i)
            csum[i] += pb[(size_t)p * 1056 + i * 256 + t];
    }
    __syncthreads();
    #pragma unroll
    for (int i = 0; i < 4; ++i) {
        int idx = i * 256 + t;
        int d = idx >> 5, e = idx & 31;
        ctx_s[d * 33 + e] = csum[i] * linv_s[d] + bv_s[e] * (1.0f / 4096.0f);
    }
    __syncthreads();
    #pragma unroll 1
    for (int it = 0; it < 8; ++it) {
        int p = it * 256 + t;
        int rt = p >> 8;
        int l = (p >> 2) & 63;
        int ip = p & 3;
        int o = rt * 16 + (l & 15);
        int d0 = (l >> 4) * 8 + 2 * ip;
        float v0 = 0.f, v1 = 0.f;
        #pragma unroll
        for (int e = 0; e < 32; ++e) {
            float wv = w_s[o * 33 + e];
            v0 = fmaf(wv, ctx_s[d0 * 33 + e], v0);
            v1 = fmaf(wv, ctx_s[(d0 + 1) * 33 + e], v1);
        }
        size_t fp = (size_t)b * 8192 + ((rt * 4 + h) * 64 + l) * 4 + ip;
        mpk[fp] = pack2(v0 * SCALE, v1 * SCALE);
    }
}

// grid (tile32=128, b=16) = 2048 blocks, 256 threads. GEMM2: out = M.qs
// + b_out, 32 px per block, M single-bf16 (16 MFMA per wave).
__global__ __launch_bounds__(256) void out_kernel(
    const uint4* __restrict__ qs, const unsigned* __restrict__ mpk,
    const float* __restrict__ b_out, float* __restrict__ out)
{
    __shared__ float bias_o[128];
    const int t = threadIdx.x;
    const int tile32 = blockIdx.x, b = blockIdx.y;
    const int chunk = tile32 >> 1;
    const int nb = (tile32 & 1) * 2;     // nt base: 0 or 2
    const int lane = t & 63;
    const int w = __builtin_amdgcn_readfirstlane(t >> 6);
    const int lg = lane >> 4, l15 = lane & 15;
    if (t < 128) bias_o[t] = b_out[t];
    __syncthreads();

    const uint4* q4 = qs + ((size_t)b * 64 + chunk) * 1024;
    const uint4* mp4 = (const uint4*)(mpk + (size_t)b * 8192);
    f32x4 acc2[2][2];
    #pragma unroll
    for (int rt = 0; rt < 2; ++rt)
        #pragma unroll
        for (int n2 = 0; n2 < 2; ++n2)
            acc2[rt][n2] = (f32x4){0.f, 0.f, 0.f, 0.f};
    #pragma unroll
    for (int ks = 0; ks < 4; ++ks) {
        bf16x8 bh[2];
        #pragma unroll
        for (int n2 = 0; n2 < 2; ++n2)
            bh[n2] = __builtin_bit_cast(bf16x8,
                q4[(ks * 4 + lg) * 64 + (nb + n2) * 16 + l15]);
        #pragma unroll
        for (int rt = 0; rt < 2; ++rt) {
            bf16x8 ah = __builtin_bit_cast(bf16x8,
                mp4[((2 * w + rt) * 4 + ks) * 64 + lane]);
            #pragma unroll
            for (int n2 = 0; n2 < 2; ++n2)
                acc2[rt][n2] = __builtin_amdgcn_mfma_f32_16x16x32_bf16(ah, bh[n2], acc2[rt][n2], 0, 0, 0);
        }
    }
    float* ob = out + (size_t)b * (128 * 4096) + chunk * 64;
    #pragma unroll
    for (int rt = 0; rt < 2; ++rt)
        #pragma unroll
        for (int r = 0; r < 4; ++r) {
            int ch = w * 32 + rt * 16 + lg * 4 + r;
            float bo = bias_o[ch];
            #pragma unroll
            for (int n2 = 0; n2 < 2; ++n2)
                ob[(size_t)ch * 4096 + (nb + n2) * 16 + l15] = acc2[rt][n2][r] + bo;
        }
}

extern "C" void kernel_launch(void* const* d_in, const int* in_sizes, int n_in,
                              void* d_out, int out_size, void* d_ws, size_t ws_size,
                              hipStream_t stream) {
    const float* x     = (const float*)d_in[0];
    const float* w_qkv = (const float*)d_in[1];
    const float* wA_q  = (const float*)d_in[2];
    const float* bA_q  = (const float*)d_in[3];
    const float* wB_q  = (const float*)d_in[4];
    const float* bB_q  = (const float*)d_in[5];
    const float* wA_k  = (const float*)d_in[6];
    const float* bA_k  = (const float*)d_in[7];
    const float* wB_k  = (const float*)d_in[8];
    const float* bB_k  = (const float*)d_in[9];
    const float* wA_v  = (const float*)d_in[10];
    const float* bA_v  = (const float*)d_in[11];
    const float* wB_v  = (const float*)d_in[12];
    const float* bB_v  = (const float*)d_in[13];
    const float* w_out = (const float*)d_in[14];
    const float* b_out = (const float*)d_in[15];
    float* out = (float*)d_out;

    float* ws = (float*)d_ws;
    float*    beff  = ws;                             // 384 f
    float*    part  = ws + 384;                       // 4325376 f
    float*    part2 = ws + 4325760;                   // 540672 f
    unsigned* wq    = (unsigned*)(ws + 4866432);      // 8192 u32
    unsigned* wkv   = (unsigned*)(ws + 4874624);      // 16384 u32
    unsigned* mpk   = (unsigned*)(ws + 4891008);      // 131072 u32
    uint4*    qs    = (uint4*)(ws + 5022080);         // 65536 uint4

    prep_kernel<<<97, 256, 0, stream>>>(w_qkv,
        wA_q, bA_q, wB_q, bB_q, wA_k, bA_k, wB_k, bB_k, wA_v, bA_v, wB_v, bB_v,
        wq, wkv, beff);
    ctx_fused_kernel<<<dim3(NCHUNK, 16), 256, 0, stream>>>(x, wq, wkv, beff,
        part, qs);
    combine_a_kernel<<<dim3(4, 16, 8), 256, 0, stream>>>(part, part2);
    combine_b_kernel<<<dim3(4, 16), 256, 0, stream>>>(part2, w_out, beff, mpk);
    out_kernel<<<dim3(128, 16), 256, 0, stream>>>(qs, mpk, b_out, out);
}

// Round 22
// 51.068 us; speedup vs baseline: 1.1362x; 1.0583x over previous
//
#include <hip/hip_runtime.h>

// loraLinearAttention on MI355X.
// R21->R22: two traffic cuts on the R19/R21 baseline (54.0us), both
// previously validated in isolation:
// (1) part bf16-packed (R20-validated numerics: absmax 7.45e-9 unchanged;
//     17.3MB f32 -> 8.9MB packed, saves ~2.7us across ctx-write+combine_a).
// (2) out_kernel back to 64-px tiles (R18 geometry) with single-bf16 M
//     (R19-validated): each qs chunk read ONCE (16MB not 32MB, ~-2.5us),
//     32 MFMA/wave (half of R18's hi/lo version).
// ctx/prep/combine_b unchanged from R21.

typedef float f32x4 __attribute__((ext_vector_type(4)));
typedef short bf16x8 __attribute__((ext_vector_type(8)));

#define SCALING 0.25f
#define SCALE   0.17677669529663687f   /* 32^-0.5 */
#define NCHUNK  64                     /* 64-px chunks per (b,h) */
#define PSTRIDE 544                    /* u32 per (b,h,chunk): 512 ctx pairs + 32 l */

__device__ __forceinline__ unsigned short f2bf_rn(float x) {
    union { float f; unsigned u; } v; v.f = x;
    unsigned r = v.u + 0x7FFFu + ((v.u >> 16) & 1u);
    return (unsigned short)(r >> 16);
}
__device__ __forceinline__ float bf2f(unsigned h16) {
    union { unsigned u; float f; } v; v.u = h16 << 16;
    return v.f;
}
__device__ __forceinline__ unsigned pack2(float a, float b) {
    return (unsigned)f2bf_rn(a) | ((unsigned)f2bf_rn(b) << 16);
}

__device__ __forceinline__ float weff(
    const float* __restrict__ w_qkv, const float* __restrict__ wA,
    const float* __restrict__ wB, int m, int o, int c)
{
    float s = w_qkv[(m * 128 + o) * 128 + c];
    #pragma unroll
    for (int r = 0; r < 4; ++r)
        s += SCALING * wB[o * 4 + r] * wA[r * 128 + c];
    return s;
}

// grid 97 x 256. tid<8192: Wq A-frag single-bf16 pairs; 8192..24575: Wkv.
// Block 96: beff (q bias for softmax, v bias for combine; k bias dropped).
__global__ __launch_bounds__(256) void prep_kernel(
    const float* __restrict__ w_qkv,
    const float* __restrict__ wA_q, const float* __restrict__ bA_q,
    const float* __restrict__ wB_q, const float* __restrict__ bB_q,
    const float* __restrict__ wA_k, const float* __restrict__ bA_k,
    const float* __restrict__ wB_k, const float* __restrict__ bB_k,
    const float* __restrict__ wA_v, const float* __restrict__ bA_v,
    const float* __restrict__ wB_v, const float* __restrict__ bB_v,
    unsigned* __restrict__ wq, unsigned* __restrict__ wkv,
    float* __restrict__ beff)
{
    const int t = threadIdx.x;
    if (blockIdx.x == 96) {
        for (int ii = t; ii < 384; ii += 256) {
            int mm = ii >> 7, oo = ii & 127;
            const float* wBm = (mm == 0) ? wB_q : (mm == 1) ? wB_k : wB_v;
            const float* bAm = (mm == 0) ? bA_q : (mm == 1) ? bA_k : bA_v;
            const float* bBm = (mm == 0) ? bB_q : (mm == 1) ? bB_k : bB_v;
            float bb = bBm[oo];
            #pragma unroll
            for (int r = 0; r < 4; ++r) bb += wBm[oo * 4 + r] * bAm[r];
            beff[ii] = SCALING * bb;
        }
        return;
    }
    int tid = blockIdx.x * 256 + t;
    if (tid < 8192) {                       // Wq A-frag, single bf16
        int fp = tid;
        int f = fp * 2;
        int i = f & 7;
        int l = (f >> 3) & 63;
        int rgks = f >> 9;                  // 0..31
        int rg = rgks >> 2, ks = rgks & 3;  // rg 0..7
        int o = rg * 16 + (l & 15);         // q row 0..127
        int c = ks * 32 + ((l >> 4) & 3) * 8 + i;
        wq[fp] = pack2(weff(w_qkv, wA_q, wB_q, 0, o, c),
                       weff(w_qkv, wA_q, wB_q, 0, o, c + 1));
    } else {                                // Wkv A-frag, single bf16
        int fp = tid - 8192;
        int f = fp * 2;
        int i = f & 7;
        int l = (f >> 3) & 63;
        int rtks = f >> 9;                  // 0..63
        int rt = rtks >> 2, ks = rtks & 3;  // rt 0..15
        int row = rt * 16 + (l & 15);       // kv row 0..255
        int c = ks * 32 + ((l >> 4) & 3) * 8 + i;
        int m = 1 + (row >> 7), o = row & 127;
        const float* wA = (m == 1) ? wA_k : wA_v;
        const float* wB = (m == 1) ? wB_k : wB_v;
        wkv[fp] = pack2(weff(w_qkv, wA, wB, m, o, c),
                        weff(w_qkv, wA, wB, m, o, c + 1));
    }
}

// grid (chunk=64, b=16) = 1024 blocks, 256 threads (4 waves), 36.9KB LDS.
// Wave w, sequentially: stage x quarter -> q head w (32 MFMA, softmax,
// qs->global) -> kv rows 64w (32 MFMA, exp for w<2, early pack) -> barrier
// -> kv->LDS -> barrier -> ctx P.V^T + l -> part (bf16-packed pairs).
__global__ __launch_bounds__(256) void ctx_fused_kernel(
    const float* __restrict__ x, const unsigned* __restrict__ wq,
    const unsigned* __restrict__ wkv, const float* __restrict__ beff,
    unsigned* __restrict__ part, uint4* __restrict__ qs)
{
    __shared__ __align__(16) char smem[36864];
    uint4* xs = (uint4*)smem;                     // 16 KB (dead after GEMM1s)
    unsigned short* kv = (unsigned short*)smem;   // [256][72] bf16
    const int t = threadIdx.x;
    const int lane = t & 63;
    const int w = __builtin_amdgcn_readfirstlane(t >> 6);  // 0..3
    const int chunk = blockIdx.x, b = blockIdx.y;
    const int lg = lane >> 4, l15 = lane & 15;
    const float* xb = x + (size_t)b * (128 * 4096);
    const int n0 = chunk * 64;
    const uint4* wq4 = (const uint4*)wq;
    const uint4* wkv4 = (const uint4*)wkv;

    // stage x single-bf16 B-frags: wave w -> channel groups p*4+w (p=0..3),
    // issued as two 16-load groups for deeper in-flight load queues.
    #pragma unroll
    for (int pp = 0; pp < 2; ++pp) {
        float v[16];
        #pragma unroll
        for (int g2 = 0; g2 < 2; ++g2) {
            int g = (pp * 2 + g2) * 4 + w;
            #pragma unroll
            for (int j = 0; j < 8; ++j)
                v[g2 * 8 + j] = xb[(size_t)(g * 8 + j) * 4096 + n0 + lane];
        }
        #pragma unroll
        for (int g2 = 0; g2 < 2; ++g2) {
            int g = (pp * 2 + g2) * 4 + w;
            xs[g * 64 + lane] = make_uint4(
                pack2(v[g2*8+0], v[g2*8+1]), pack2(v[g2*8+2], v[g2*8+3]),
                pack2(v[g2*8+4], v[g2*8+5]), pack2(v[g2*8+6], v[g2*8+7]));
        }
    }
    __syncthreads();

    // ===== q: head w, rows 32w+16rt+lg*4+r =====
    {
        f32x4 acc[2][4];
        #pragma unroll
        for (int rt = 0; rt < 2; ++rt)
            #pragma unroll
            for (int nt = 0; nt < 4; ++nt)
                acc[rt][nt] = (f32x4){0.f, 0.f, 0.f, 0.f};
        #pragma unroll
        for (int ks = 0; ks < 4; ++ks) {
            bf16x8 bh[4];
            #pragma unroll
            for (int nt = 0; nt < 4; ++nt)
                bh[nt] = __builtin_bit_cast(bf16x8, xs[(ks * 4 + lg) * 64 + nt * 16 + l15]);
            #pragma unroll
            for (int rt = 0; rt < 2; ++rt) {
                bf16x8 ah = __builtin_bit_cast(bf16x8,
                    wq4[((2 * w + rt) * 4 + ks) * 64 + lane]);
                #pragma unroll
                for (int nt = 0; nt < 4; ++nt)
                    acc[rt][nt] = __builtin_amdgcn_mfma_f32_16x16x32_bf16(ah, bh[nt], acc[rt][nt], 0, 0, 0);
            }
        }
        float bq[2][4];
        #pragma unroll
        for (int rt = 0; rt < 2; ++rt)
            #pragma unroll
            for (int r = 0; r < 4; ++r)
                bq[rt][r] = beff[w * 32 + rt * 16 + lg * 4 + r];
        #pragma unroll
        for (int nt = 0; nt < 4; ++nt) {
            float m = -1e30f;
            #pragma unroll
            for (int rt = 0; rt < 2; ++rt)
                #pragma unroll
                for (int r = 0; r < 4; ++r) {
                    float q = acc[rt][nt][r] + bq[rt][r];
                    acc[rt][nt][r] = q;
                    m = fmaxf(m, q);
                }
            m = fmaxf(m, __shfl_xor(m, 16));
            m = fmaxf(m, __shfl_xor(m, 32));
            float s = 0.f;
            #pragma unroll
            for (int rt = 0; rt < 2; ++rt)
                #pragma unroll
                for (int r = 0; r < 4; ++r) {
                    float e = __expf(acc[rt][nt][r] - m);
                    acc[rt][nt][r] = e;
                    s += e;
                }
            s += __shfl_xor(s, 16);
            s += __shfl_xor(s, 32);
            float inv = 1.0f / s;
            #pragma unroll
            for (int rt = 0; rt < 2; ++rt)
                #pragma unroll
                for (int r = 0; r < 4; ++r)
                    acc[rt][nt][r] *= inv;
        }
        uint2* q2g = (uint2*)(qs + ((size_t)b * 64 + chunk) * 1024);
        int half = (lg & 1);
        #pragma unroll
        for (int rt = 0; rt < 2; ++rt) {
            int kb = rt * 2 + (lg >> 1);
            #pragma unroll
            for (int nt = 0; nt < 4; ++nt) {
                int idx = ((w * 4 + kb) * 64 + nt * 16 + l15) * 2 + half;
                q2g[idx] = make_uint2(pack2(acc[rt][nt][0], acc[rt][nt][1]),
                                      pack2(acc[rt][nt][2], acc[rt][nt][3]));
            }
        }
    }

    // ===== kv: rows 64w..+63; exp for K (w<2); early bf16 pack =====
    unsigned pk[4][8];
    #pragma unroll
    for (int rt = 0; rt < 4; ++rt) {
        f32x4 acc[4];
        #pragma unroll
        for (int nt = 0; nt < 4; ++nt) acc[nt] = (f32x4){0.f, 0.f, 0.f, 0.f};
        #pragma unroll
        for (int ks = 0; ks < 4; ++ks) {
            bf16x8 ah = __builtin_bit_cast(bf16x8,
                wkv4[((4 * w + rt) * 4 + ks) * 64 + lane]);
            #pragma unroll
            for (int nt = 0; nt < 4; ++nt) {
                bf16x8 bh = __builtin_bit_cast(bf16x8,
                    xs[(ks * 4 + lg) * 64 + nt * 16 + l15]);
                acc[nt] = __builtin_amdgcn_mfma_f32_16x16x32_bf16(ah, bh, acc[nt], 0, 0, 0);
            }
        }
        #pragma unroll
        for (int nt = 0; nt < 4; ++nt) {
            float v0 = acc[nt][0], v1 = acc[nt][1];
            float v2 = acc[nt][2], v3 = acc[nt][3];
            if (w < 2) {                 // K waves: exp in regs
                v0 = __expf(v0); v1 = __expf(v1);
                v2 = __expf(v2); v3 = __expf(v3);
            }
            pk[rt][nt * 2]     = pack2(v0, v1);
            pk[rt][nt * 2 + 1] = pack2(v2, v3);
        }
    }
    __syncthreads();                     // all xs reads done (kv overwrites)
    #pragma unroll
    for (int rt = 0; rt < 4; ++rt)
        #pragma unroll
        for (int nt = 0; nt < 4; ++nt)
            #pragma unroll
            for (int rr = 0; rr < 2; ++rr) {
                unsigned u = pk[rt][nt * 2 + rr];
                int row0 = 64 * w + 16 * rt + lg * 4 + rr * 2;
                int px = nt * 16 + l15;
                kv[row0 * 72 + px] = (unsigned short)u;
                kv[(row0 + 1) * 72 + px] = (unsigned short)(u >> 16);
            }
    __syncthreads();

    // ===== ctx: head w (P rows 32w.., V rows 128+32w..) + l =====
    bf16x8 ones;
    #pragma unroll
    for (int i = 0; i < 8; ++i) ones[i] = (short)0x3F80;
    f32x4 ctx_acc[2][2];
    f32x4 l_acc[2];
    #pragma unroll
    for (int rt = 0; rt < 2; ++rt) {
        l_acc[rt] = (f32x4){0.f, 0.f, 0.f, 0.f};
        #pragma unroll
        for (int et = 0; et < 2; ++et)
            ctx_acc[rt][et] = (f32x4){0.f, 0.f, 0.f, 0.f};
    }
    #pragma unroll
    for (int ks2 = 0; ks2 < 2; ++ks2) {
        int pxb = ks2 * 32 + lg * 8;
        bf16x8 ph[2], vh[2];
        #pragma unroll
        for (int rt = 0; rt < 2; ++rt)
            ph[rt] = __builtin_bit_cast(bf16x8, *(const uint4*)&kv[(32 * w + 16 * rt + l15) * 72 + pxb]);
        #pragma unroll
        for (int et = 0; et < 2; ++et)
            vh[et] = __builtin_bit_cast(bf16x8, *(const uint4*)&kv[(128 + 32 * w + 16 * et + l15) * 72 + pxb]);
        #pragma unroll
        for (int rt = 0; rt < 2; ++rt) {
            #pragma unroll
            for (int et = 0; et < 2; ++et)
                ctx_acc[rt][et] = __builtin_amdgcn_mfma_f32_16x16x32_bf16(ph[rt], vh[et], ctx_acc[rt][et], 0, 0, 0);
            l_acc[rt] = __builtin_amdgcn_mfma_f32_16x16x32_bf16(ph[rt], ones, l_acc[rt], 0, 0, 0);
        }
    }
    // part write, bf16-packed: u32[d*16+l15] = pack2(ctx[d][l15], ctx[d][16+l15])
    unsigned* pout = part + (size_t)((b * 4 + w) * NCHUNK + chunk) * PSTRIDE;
    #pragma unroll
    for (int rt = 0; rt < 2; ++rt) {
        #pragma unroll
        for (int r = 0; r < 4; ++r) {
            int d = 16 * rt + lg * 4 + r;
            pout[d * 16 + l15] = pack2(ctx_acc[rt][0][r], ctx_acc[rt][1][r]);
        }
        if (l15 == 0)
            #pragma unroll
            for (int r = 0; r < 4; ++r)
                pout[512 + 16 * rt + lg * 4 + r] = __float_as_uint(l_acc[rt][r]);
    }
}

// grid (4 heads, 16 b, 8 groups), 256 threads: partial-reduce 8 chunks
// (bf16 unpack -> f32 sums; part2 f32 layout [d*32+e] + l @1024).
__global__ __launch_bounds__(256) void combine_a_kernel(
    const unsigned* __restrict__ part, float* __restrict__ part2)
{
    const int t = threadIdx.x;
    const int h = blockIdx.x, b = blockIdx.y, g = blockIdx.z;
    const unsigned* pb = part + (size_t)((b * 4 + h) * NCHUNK + g * 8) * PSTRIDE;
    float slo[2] = {0.f, 0.f}, shi[2] = {0.f, 0.f};
    #pragma unroll 1
    for (int ch = 0; ch < 8; ++ch) {
        #pragma unroll
        for (int i = 0; i < 2; ++i) {
            unsigned u = pb[(size_t)ch * PSTRIDE + i * 256 + t];
            slo[i] += bf2f(u & 0xFFFFu);
            shi[i] += bf2f(u >> 16);
        }
    }
    float* po = part2 + (size_t)(((b * 4 + h) * 8) + g) * 1056;
    #pragma unroll
    for (int i = 0; i < 2; ++i) {
        int p = i * 256 + t;
        int d = p >> 4, e = p & 15;
        po[d * 32 + e] = slo[i];
        po[d * 32 + 16 + e] = shi[i];
    }
    if (t < 32) {
        float l = 0.f;
        #pragma unroll
        for (int ch = 0; ch < 8; ++ch)
            l += __uint_as_float(pb[(size_t)ch * PSTRIDE + 512 + t]);
        po[1024 + t] = l;
    }
}

// grid (4 heads, 16 batches), 256 threads: final reduce + normalize +
// M-pack (SINGLE bf16). Unchanged from R21.
__global__ __launch_bounds__(256) void combine_b_kernel(
    const float* __restrict__ part2, const float* __restrict__ w_out,
    const float* __restrict__ beff, unsigned* __restrict__ mpk)
{
    __shared__ float ctx_s[32 * 33];
    __shared__ float w_s[128 * 33];
    __shared__ float linv_s[32];
    __shared__ float bv_s[32];
    const int t = threadIdx.x;
    const int h = blockIdx.x, b = blockIdx.y;
    const float* pb = part2 + (size_t)((b * 4 + h) * 8) * 1056;

    if (t < 32) {
        float l = 0.f;
        #pragma unroll
        for (int p = 0; p < 8; ++p) l += pb[(size_t)p * 1056 + 1024 + t];
        linv_s[t] = 1.0f / (l * 4096.0f);
        bv_s[t] = beff[256 + h * 32 + t];
    }
    #pragma unroll
    for (int i = 0; i < 16; ++i) {
        int idx = i * 256 + t;
        int e = idx & 31, o = idx >> 5;
        w_s[o * 33 + e] = w_out[o * 128 + h * 32 + e];
    }
    float csum[4] = {0.f, 0.f, 0.f, 0.f};
    #pragma unroll
    for (int p = 0; p < 8; ++p) {
        #pragma unroll
        for (int i = 0; i < 4; ++i)
            csum[i] += pb[(size_t)p * 1056 + i * 256 + t];
    }
    __syncthreads();
    #pragma unroll
    for (int i = 0; i < 4; ++i) {
        int idx = i * 256 + t;
        int d = idx >> 5, e = idx & 31;
        ctx_s[d * 33 + e] = csum[i] * linv_s[d] + bv_s[e] * (1.0f / 4096.0f);
    }
    __syncthreads();
    #pragma unroll 1
    for (int it = 0; it < 8; ++it) {
        int p = it * 256 + t;
        int rt = p >> 8;
        int l = (p >> 2) & 63;
        int ip = p & 3;
        int o = rt * 16 + (l & 15);
        int d0 = (l >> 4) * 8 + 2 * ip;
        float v0 = 0.f, v1 = 0.f;
        #pragma unroll
        for (int e = 0; e < 32; ++e) {
            float wv = w_s[o * 33 + e];
            v0 = fmaf(wv, ctx_s[d0 * 33 + e], v0);
            v1 = fmaf(wv, ctx_s[(d0 + 1) * 33 + e], v1);
        }
        size_t fp = (size_t)b * 8192 + ((rt * 4 + h) * 64 + l) * 4 + ip;
        mpk[fp] = pack2(v0 * SCALE, v1 * SCALE);
    }
}

// grid (tile=64, b=16) = 1024 blocks, 256 threads. GEMM2: out = M.qs
// + b_out, 64 px per block (qs chunk read ONCE), M single-bf16 (32 MFMA).
__global__ __launch_bounds__(256) void out_kernel(
    const uint4* __restrict__ qs, const unsigned* __restrict__ mpk,
    const float* __restrict__ b_out, float* __restrict__ out)
{
    __shared__ float bias_o[128];
    const int t = threadIdx.x;
    const int tile = blockIdx.x, b = blockIdx.y;
    const int lane = t & 63;
    const int w = __builtin_amdgcn_readfirstlane(t >> 6);
    const int lg = lane >> 4, l15 = lane & 15;
    if (t < 128) bias_o[t] = b_out[t];
    __syncthreads();

    const uint4* q4 = qs + ((size_t)b * 64 + tile) * 1024;
    const uint4* mp4 = (const uint4*)(mpk + (size_t)b * 8192);
    f32x4 acc2[2][4];
    #pragma unroll
    for (int rt = 0; rt < 2; ++rt)
        #pragma unroll
        for (int nt = 0; nt < 4; ++nt)
            acc2[rt][nt] = (f32x4){0.f, 0.f, 0.f, 0.f};
    #pragma unroll
    for (int ks = 0; ks < 4; ++ks) {
        bf16x8 bh[4];
        #pragma unroll
        for (int nt = 0; nt < 4; ++nt)
            bh[nt] = __builtin_bit_cast(bf16x8, q4[(ks * 4 + lg) * 64 + nt * 16 + l15]);
        #pragma unroll
        for (int rt = 0; rt < 2; ++rt) {
            bf16x8 ah = __builtin_bit_cast(bf16x8,
                mp4[((2 * w + rt) * 4 + ks) * 64 + lane]);
            #pragma unroll
            for (int nt = 0; nt < 4; ++nt)
                acc2[rt][nt] = __builtin_amdgcn_mfma_f32_16x16x32_bf16(ah, bh[nt], acc2[rt][nt], 0, 0, 0);
        }
    }
    float* ob = out + (size_t)b * (128 * 4096) + tile * 64;
    #pragma unroll
    for (int rt = 0; rt < 2; ++rt)
        #pragma unroll
        for (int r = 0; r < 4; ++r) {
            int ch = w * 32 + rt * 16 + lg * 4 + r;
            float bo = bias_o[ch];
            #pragma unroll
            for (int nt = 0; nt < 4; ++nt)
                ob[(size_t)ch * 4096 + nt * 16 + l15] = acc2[rt][nt][r] + bo;
        }
}

extern "C" void kernel_launch(void* const* d_in, const int* in_sizes, int n_in,
                              void* d_out, int out_size, void* d_ws, size_t ws_size,
                              hipStream_t stream) {
    const float* x     = (const float*)d_in[0];
    const float* w_qkv = (const float*)d_in[1];
    const float* wA_q  = (const float*)d_in[2];
    const float* bA_q  = (const float*)d_in[3];
    const float* wB_q  = (const float*)d_in[4];
    const float* bB_q  = (const float*)d_in[5];
    const float* wA_k  = (const float*)d_in[6];
    const float* bA_k  = (const float*)d_in[7];
    const float* wB_k  = (const float*)d_in[8];
    const float* bB_k  = (const float*)d_in[9];
    const float* wA_v  = (const float*)d_in[10];
    const float* bA_v  = (const float*)d_in[11];
    const float* wB_v  = (const float*)d_in[12];
    const float* bB_v  = (const float*)d_in[13];
    const float* w_out = (const float*)d_in[14];
    const float* b_out = (const float*)d_in[15];
    float* out = (float*)d_out;

    float* ws = (float*)d_ws;
    float*    beff  = ws;                             // 384 f
    unsigned* part  = (unsigned*)(ws + 384);          // 16*4*64*544 = 2228224 u32
    float*    part2 = ws + 384 + 2228224;             // 540672 f
    unsigned* wq    = (unsigned*)(ws + 2769280);      // 8192 u32
    unsigned* wkv   = (unsigned*)(ws + 2777472);      // 16384 u32
    unsigned* mpk   = (unsigned*)(ws + 2793856);      // 131072 u32
    uint4*    qs    = (uint4*)(ws + 2924928);         // 1048576 uint4 (16 MB)

    prep_kernel<<<97, 256, 0, stream>>>(w_qkv,
        wA_q, bA_q, wB_q, bB_q, wA_k, bA_k, wB_k, bB_k, wA_v, bA_v, wB_v, bB_v,
        wq, wkv, beff);
    ctx_fused_kernel<<<dim3(NCHUNK, 16), 256, 0, stream>>>(x, wq, wkv, beff,
        part, qs);
    combine_a_kernel<<<dim3(4, 16, 8), 256, 0, stream>>>(part, part2);
    combine_b_kernel<<<dim3(4, 16), 256, 0, stream>>>(part2, w_out, beff, mpk);
    out_kernel<<<dim3(64, 16), 256, 0, stream>>>(qs, mpk, b_out, out);
}

// Round 23
// 50.595 us; speedup vs baseline: 1.1468x; 1.0093x over previous
//
#include <hip/hip_runtime.h>

// loraLinearAttention on MI355X.
// R22->R23: micro bundle. (1) out_kernel bias via direct global loads -
// removes LDS staging AND the kernel's only barrier. (2) combine_a z-groups
// 8->16 (1024 blocks, 4 chunks each); combine_b reduces 16 partials.
// Everything else unchanged from R22 (51.07us, absmax 7.45e-9).

typedef float f32x4 __attribute__((ext_vector_type(4)));
typedef short bf16x8 __attribute__((ext_vector_type(8)));

#define SCALING 0.25f
#define SCALE   0.17677669529663687f   /* 32^-0.5 */
#define NCHUNK  64                     /* 64-px chunks per (b,h) */
#define PSTRIDE 544                    /* u32 per (b,h,chunk): 512 ctx pairs + 32 l */

__device__ __forceinline__ unsigned short f2bf_rn(float x) {
    union { float f; unsigned u; } v; v.f = x;
    unsigned r = v.u + 0x7FFFu + ((v.u >> 16) & 1u);
    return (unsigned short)(r >> 16);
}
__device__ __forceinline__ float bf2f(unsigned h16) {
    union { unsigned u; float f; } v; v.u = h16 << 16;
    return v.f;
}
__device__ __forceinline__ unsigned pack2(float a, float b) {
    return (unsigned)f2bf_rn(a) | ((unsigned)f2bf_rn(b) << 16);
}

__device__ __forceinline__ float weff(
    const float* __restrict__ w_qkv, const float* __restrict__ wA,
    const float* __restrict__ wB, int m, int o, int c)
{
    float s = w_qkv[(m * 128 + o) * 128 + c];
    #pragma unroll
    for (int r = 0; r < 4; ++r)
        s += SCALING * wB[o * 4 + r] * wA[r * 128 + c];
    return s;
}

// grid 97 x 256. tid<8192: Wq A-frag single-bf16 pairs; 8192..24575: Wkv.
// Block 96: beff (q bias for softmax, v bias for combine; k bias dropped).
__global__ __launch_bounds__(256) void prep_kernel(
    const float* __restrict__ w_qkv,
    const float* __restrict__ wA_q, const float* __restrict__ bA_q,
    const float* __restrict__ wB_q, const float* __restrict__ bB_q,
    const float* __restrict__ wA_k, const float* __restrict__ bA_k,
    const float* __restrict__ wB_k, const float* __restrict__ bB_k,
    const float* __restrict__ wA_v, const float* __restrict__ bA_v,
    const float* __restrict__ wB_v, const float* __restrict__ bB_v,
    unsigned* __restrict__ wq, unsigned* __restrict__ wkv,
    float* __restrict__ beff)
{
    const int t = threadIdx.x;
    if (blockIdx.x == 96) {
        for (int ii = t; ii < 384; ii += 256) {
            int mm = ii >> 7, oo = ii & 127;
            const float* wBm = (mm == 0) ? wB_q : (mm == 1) ? wB_k : wB_v;
            const float* bAm = (mm == 0) ? bA_q : (mm == 1) ? bA_k : bA_v;
            const float* bBm = (mm == 0) ? bB_q : (mm == 1) ? bB_k : bB_v;
            float bb = bBm[oo];
            #pragma unroll
            for (int r = 0; r < 4; ++r) bb += wBm[oo * 4 + r] * bAm[r];
            beff[ii] = SCALING * bb;
        }
        return;
    }
    int tid = blockIdx.x * 256 + t;
    if (tid < 8192) {                       // Wq A-frag, single bf16
        int fp = tid;
        int f = fp * 2;
        int i = f & 7;
        int l = (f >> 3) & 63;
        int rgks = f >> 9;                  // 0..31
        int rg = rgks >> 2, ks = rgks & 3;  // rg 0..7
        int o = rg * 16 + (l & 15);         // q row 0..127
        int c = ks * 32 + ((l >> 4) & 3) * 8 + i;
        wq[fp] = pack2(weff(w_qkv, wA_q, wB_q, 0, o, c),
                       weff(w_qkv, wA_q, wB_q, 0, o, c + 1));
    } else {                                // Wkv A-frag, single bf16
        int fp = tid - 8192;
        int f = fp * 2;
        int i = f & 7;
        int l = (f >> 3) & 63;
        int rtks = f >> 9;                  // 0..63
        int rt = rtks >> 2, ks = rtks & 3;  // rt 0..15
        int row = rt * 16 + (l & 15);       // kv row 0..255
        int c = ks * 32 + ((l >> 4) & 3) * 8 + i;
        int m = 1 + (row >> 7), o = row & 127;
        const float* wA = (m == 1) ? wA_k : wA_v;
        const float* wB = (m == 1) ? wB_k : wB_v;
        wkv[fp] = pack2(weff(w_qkv, wA, wB, m, o, c),
                        weff(w_qkv, wA, wB, m, o, c + 1));
    }
}

// grid (chunk=64, b=16) = 1024 blocks, 256 threads (4 waves), 36.9KB LDS.
// Wave w, sequentially: stage x quarter -> q head w (32 MFMA, softmax,
// qs->global) -> kv rows 64w (32 MFMA, exp for w<2, early pack) -> barrier
// -> kv->LDS -> barrier -> ctx P.V^T + l -> part (bf16-packed pairs).
__global__ __launch_bounds__(256) void ctx_fused_kernel(
    const float* __restrict__ x, const unsigned* __restrict__ wq,
    const unsigned* __restrict__ wkv, const float* __restrict__ beff,
    unsigned* __restrict__ part, uint4* __restrict__ qs)
{
    __shared__ __align__(16) char smem[36864];
    uint4* xs = (uint4*)smem;                     // 16 KB (dead after GEMM1s)
    unsigned short* kv = (unsigned short*)smem;   // [256][72] bf16
    const int t = threadIdx.x;
    const int lane = t & 63;
    const int w = __builtin_amdgcn_readfirstlane(t >> 6);  // 0..3
    const int chunk = blockIdx.x, b = blockIdx.y;
    const int lg = lane >> 4, l15 = lane & 15;
    const float* xb = x + (size_t)b * (128 * 4096);
    const int n0 = chunk * 64;
    const uint4* wq4 = (const uint4*)wq;
    const uint4* wkv4 = (const uint4*)wkv;

    // stage x single-bf16 B-frags: wave w -> channel groups p*4+w (p=0..3),
    // issued as two 16-load groups for deeper in-flight load queues.
    #pragma unroll
    for (int pp = 0; pp < 2; ++pp) {
        float v[16];
        #pragma unroll
        for (int g2 = 0; g2 < 2; ++g2) {
            int g = (pp * 2 + g2) * 4 + w;
            #pragma unroll
            for (int j = 0; j < 8; ++j)
                v[g2 * 8 + j] = xb[(size_t)(g * 8 + j) * 4096 + n0 + lane];
        }
        #pragma unroll
        for (int g2 = 0; g2 < 2; ++g2) {
            int g = (pp * 2 + g2) * 4 + w;
            xs[g * 64 + lane] = make_uint4(
                pack2(v[g2*8+0], v[g2*8+1]), pack2(v[g2*8+2], v[g2*8+3]),
                pack2(v[g2*8+4], v[g2*8+5]), pack2(v[g2*8+6], v[g2*8+7]));
        }
    }
    __syncthreads();

    // ===== q: head w, rows 32w+16rt+lg*4+r =====
    {
        f32x4 acc[2][4];
        #pragma unroll
        for (int rt = 0; rt < 2; ++rt)
            #pragma unroll
            for (int nt = 0; nt < 4; ++nt)
                acc[rt][nt] = (f32x4){0.f, 0.f, 0.f, 0.f};
        #pragma unroll
        for (int ks = 0; ks < 4; ++ks) {
            bf16x8 bh[4];
            #pragma unroll
            for (int nt = 0; nt < 4; ++nt)
                bh[nt] = __builtin_bit_cast(bf16x8, xs[(ks * 4 + lg) * 64 + nt * 16 + l15]);
            #pragma unroll
            for (int rt = 0; rt < 2; ++rt) {
                bf16x8 ah = __builtin_bit_cast(bf16x8,
                    wq4[((2 * w + rt) * 4 + ks) * 64 + lane]);
                #pragma unroll
                for (int nt = 0; nt < 4; ++nt)
                    acc[rt][nt] = __builtin_amdgcn_mfma_f32_16x16x32_bf16(ah, bh[nt], acc[rt][nt], 0, 0, 0);
            }
        }
        float bq[2][4];
        #pragma unroll
        for (int rt = 0; rt < 2; ++rt)
            #pragma unroll
            for (int r = 0; r < 4; ++r)
                bq[rt][r] = beff[w * 32 + rt * 16 + lg * 4 + r];
        #pragma unroll
        for (int nt = 0; nt < 4; ++nt) {
            float m = -1e30f;
            #pragma unroll
            for (int rt = 0; rt < 2; ++rt)
                #pragma unroll
                for (int r = 0; r < 4; ++r) {
                    float q = acc[rt][nt][r] + bq[rt][r];
                    acc[rt][nt][r] = q;
                    m = fmaxf(m, q);
                }
            m = fmaxf(m, __shfl_xor(m, 16));
            m = fmaxf(m, __shfl_xor(m, 32));
            float s = 0.f;
            #pragma unroll
            for (int rt = 0; rt < 2; ++rt)
                #pragma unroll
                for (int r = 0; r < 4; ++r) {
                    float e = __expf(acc[rt][nt][r] - m);
                    acc[rt][nt][r] = e;
                    s += e;
                }
            s += __shfl_xor(s, 16);
            s += __shfl_xor(s, 32);
            float inv = 1.0f / s;
            #pragma unroll
            for (int rt = 0; rt < 2; ++rt)
                #pragma unroll
                for (int r = 0; r < 4; ++r)
                    acc[rt][nt][r] *= inv;
        }
        uint2* q2g = (uint2*)(qs + ((size_t)b * 64 + chunk) * 1024);
        int half = (lg & 1);
        #pragma unroll
        for (int rt = 0; rt < 2; ++rt) {
            int kb = rt * 2 + (lg >> 1);
            #pragma unroll
            for (int nt = 0; nt < 4; ++nt) {
                int idx = ((w * 4 + kb) * 64 + nt * 16 + l15) * 2 + half;
                q2g[idx] = make_uint2(pack2(acc[rt][nt][0], acc[rt][nt][1]),
                                      pack2(acc[rt][nt][2], acc[rt][nt][3]));
            }
        }
    }

    // ===== kv: rows 64w..+63; exp for K (w<2); early bf16 pack =====
    unsigned pk[4][8];
    #pragma unroll
    for (int rt = 0; rt < 4; ++rt) {
        f32x4 acc[4];
        #pragma unroll
        for (int nt = 0; nt < 4; ++nt) acc[nt] = (f32x4){0.f, 0.f, 0.f, 0.f};
        #pragma unroll
        for (int ks = 0; ks < 4; ++ks) {
            bf16x8 ah = __builtin_bit_cast(bf16x8,
                wkv4[((4 * w + rt) * 4 + ks) * 64 + lane]);
            #pragma unroll
            for (int nt = 0; nt < 4; ++nt) {
                bf16x8 bh = __builtin_bit_cast(bf16x8,
                    xs[(ks * 4 + lg) * 64 + nt * 16 + l15]);
                acc[nt] = __builtin_amdgcn_mfma_f32_16x16x32_bf16(ah, bh, acc[nt], 0, 0, 0);
            }
        }
        #pragma unroll
        for (int nt = 0; nt < 4; ++nt) {
            float v0 = acc[nt][0], v1 = acc[nt][1];
            float v2 = acc[nt][2], v3 = acc[nt][3];
            if (w < 2) {                 // K waves: exp in regs
                v0 = __expf(v0); v1 = __expf(v1);
                v2 = __expf(v2); v3 = __expf(v3);
            }
            pk[rt][nt * 2]     = pack2(v0, v1);
            pk[rt][nt * 2 + 1] = pack2(v2, v3);
        }
    }
    __syncthreads();                     // all xs reads done (kv overwrites)
    #pragma unroll
    for (int rt = 0; rt < 4; ++rt)
        #pragma unroll
        for (int nt = 0; nt < 4; ++nt)
            #pragma unroll
            for (int rr = 0; rr < 2; ++rr) {
                unsigned u = pk[rt][nt * 2 + rr];
                int row0 = 64 * w + 16 * rt + lg * 4 + rr * 2;
                int px = nt * 16 + l15;
                kv[row0 * 72 + px] = (unsigned short)u;
                kv[(row0 + 1) * 72 + px] = (unsigned short)(u >> 16);
            }
    __syncthreads();

    // ===== ctx: head w (P rows 32w.., V rows 128+32w..) + l =====
    bf16x8 ones;
    #pragma unroll
    for (int i = 0; i < 8; ++i) ones[i] = (short)0x3F80;
    f32x4 ctx_acc[2][2];
    f32x4 l_acc[2];
    #pragma unroll
    for (int rt = 0; rt < 2; ++rt) {
        l_acc[rt] = (f32x4){0.f, 0.f, 0.f, 0.f};
        #pragma unroll
        for (int et = 0; et < 2; ++et)
            ctx_acc[rt][et] = (f32x4){0.f, 0.f, 0.f, 0.f};
    }
    #pragma unroll
    for (int ks2 = 0; ks2 < 2; ++ks2) {
        int pxb = ks2 * 32 + lg * 8;
        bf16x8 ph[2], vh[2];
        #pragma unroll
        for (int rt = 0; rt < 2; ++rt)
            ph[rt] = __builtin_bit_cast(bf16x8, *(const uint4*)&kv[(32 * w + 16 * rt + l15) * 72 + pxb]);
        #pragma unroll
        for (int et = 0; et < 2; ++et)
            vh[et] = __builtin_bit_cast(bf16x8, *(const uint4*)&kv[(128 + 32 * w + 16 * et + l15) * 72 + pxb]);
        #pragma unroll
        for (int rt = 0; rt < 2; ++rt) {
            #pragma unroll
            for (int et = 0; et < 2; ++et)
                ctx_acc[rt][et] = __builtin_amdgcn_mfma_f32_16x16x32_bf16(ph[rt], vh[et], ctx_acc[rt][et], 0, 0, 0);
            l_acc[rt] = __builtin_amdgcn_mfma_f32_16x16x32_bf16(ph[rt], ones, l_acc[rt], 0, 0, 0);
        }
    }
    // part write, bf16-packed: u32[d*16+l15] = pack2(ctx[d][l15], ctx[d][16+l15])
    unsigned* pout = part + (size_t)((b * 4 + w) * NCHUNK + chunk) * PSTRIDE;
    #pragma unroll
    for (int rt = 0; rt < 2; ++rt) {
        #pragma unroll
        for (int r = 0; r < 4; ++r) {
            int d = 16 * rt + lg * 4 + r;
            pout[d * 16 + l15] = pack2(ctx_acc[rt][0][r], ctx_acc[rt][1][r]);
        }
        if (l15 == 0)
            #pragma unroll
            for (int r = 0; r < 4; ++r)
                pout[512 + 16 * rt + lg * 4 + r] = __float_as_uint(l_acc[rt][r]);
    }
}

// grid (4 heads, 16 b, 16 groups), 256 threads: partial-reduce 4 chunks
// (bf16 unpack -> f32 sums; part2 f32 layout [d*32+e] + l @1024).
__global__ __launch_bounds__(256) void combine_a_kernel(
    const unsigned* __restrict__ part, float* __restrict__ part2)
{
    const int t = threadIdx.x;
    const int h = blockIdx.x, b = blockIdx.y, g = blockIdx.z;
    const unsigned* pb = part + (size_t)((b * 4 + h) * NCHUNK + g * 4) * PSTRIDE;
    float slo[2] = {0.f, 0.f}, shi[2] = {0.f, 0.f};
    #pragma unroll
    for (int ch = 0; ch < 4; ++ch) {
        #pragma unroll
        for (int i = 0; i < 2; ++i) {
            unsigned u = pb[(size_t)ch * PSTRIDE + i * 256 + t];
            slo[i] += bf2f(u & 0xFFFFu);
            shi[i] += bf2f(u >> 16);
        }
    }
    float* po = part2 + (size_t)(((b * 4 + h) * 16) + g) * 1056;
    #pragma unroll
    for (int i = 0; i < 2; ++i) {
        int p = i * 256 + t;
        int d = p >> 4, e = p & 15;
        po[d * 32 + e] = slo[i];
        po[d * 32 + 16 + e] = shi[i];
    }
    if (t < 32) {
        float l = 0.f;
        #pragma unroll
        for (int ch = 0; ch < 4; ++ch)
            l += __uint_as_float(pb[(size_t)ch * PSTRIDE + 512 + t]);
        po[1024 + t] = l;
    }
}

// grid (4 heads, 16 batches), 256 threads: final reduce (16 partials) +
// normalize + M-pack (single bf16).
__global__ __launch_bounds__(256) void combine_b_kernel(
    const float* __restrict__ part2, const float* __restrict__ w_out,
    const float* __restrict__ beff, unsigned* __restrict__ mpk)
{
    __shared__ float ctx_s[32 * 33];
    __shared__ float w_s[128 * 33];
    __shared__ float linv_s[32];
    __shared__ float bv_s[32];
    const int t = threadIdx.x;
    const int h = blockIdx.x, b = blockIdx.y;
    const float* pb = part2 + (size_t)((b * 4 + h) * 16) * 1056;

    if (t < 32) {
        float l = 0.f;
        #pragma unroll
        for (int p = 0; p < 16; ++p) l += pb[(size_t)p * 1056 + 1024 + t];
        linv_s[t] = 1.0f / (l * 4096.0f);
        bv_s[t] = beff[256 + h * 32 + t];
    }
    #pragma unroll
    for (int i = 0; i < 16; ++i) {
        int idx = i * 256 + t;
        int e = idx & 31, o = idx >> 5;
        w_s[o * 33 + e] = w_out[o * 128 + h * 32 + e];
    }
    float csum[4] = {0.f, 0.f, 0.f, 0.f};
    #pragma unroll
    for (int p = 0; p < 16; ++p) {
        #pragma unroll
        for (int i = 0; i < 4; ++i)
            csum[i] += pb[(size_t)p * 1056 + i * 256 + t];
    }
    __syncthreads();
    #pragma unroll
    for (int i = 0; i < 4; ++i) {
        int idx = i * 256 + t;
        int d = idx >> 5, e = idx & 31;
        ctx_s[d * 33 + e] = csum[i] * linv_s[d] + bv_s[e] * (1.0f / 4096.0f);
    }
    __syncthreads();
    #pragma unroll 1
    for (int it = 0; it < 8; ++it) {
        int p = it * 256 + t;
        int rt = p >> 8;
        int l = (p >> 2) & 63;
        int ip = p & 3;
        int o = rt * 16 + (l & 15);
        int d0 = (l >> 4) * 8 + 2 * ip;
        float v0 = 0.f, v1 = 0.f;
        #pragma unroll
        for (int e = 0; e < 32; ++e) {
            float wv = w_s[o * 33 + e];
            v0 = fmaf(wv, ctx_s[d0 * 33 + e], v0);
            v1 = fmaf(wv, ctx_s[(d0 + 1) * 33 + e], v1);
        }
        size_t fp = (size_t)b * 8192 + ((rt * 4 + h) * 64 + l) * 4 + ip;
        mpk[fp] = pack2(v0 * SCALE, v1 * SCALE);
    }
}

// grid (tile=64, b=16) = 1024 blocks, 256 threads. GEMM2: out = M.qs
// + b_out, 64 px/block, M single-bf16 (32 MFMA). Bias from global (L2-hot),
// no LDS, no barrier.
__global__ __launch_bounds__(256) void out_kernel(
    const uint4* __restrict__ qs, const unsigned* __restrict__ mpk,
    const float* __restrict__ b_out, float* __restrict__ out)
{
    const int t = threadIdx.x;
    const int tile = blockIdx.x, b = blockIdx.y;
    const int lane = t & 63;
    const int w = __builtin_amdgcn_readfirstlane(t >> 6);
    const int lg = lane >> 4, l15 = lane & 15;

    const uint4* q4 = qs + ((size_t)b * 64 + tile) * 1024;
    const uint4* mp4 = (const uint4*)(mpk + (size_t)b * 8192);
    f32x4 acc2[2][4];
    #pragma unroll
    for (int rt = 0; rt < 2; ++rt)
        #pragma unroll
        for (int nt = 0; nt < 4; ++nt)
            acc2[rt][nt] = (f32x4){0.f, 0.f, 0.f, 0.f};
    #pragma unroll
    for (int ks = 0; ks < 4; ++ks) {
        bf16x8 bh[4];
        #pragma unroll
        for (int nt = 0; nt < 4; ++nt)
            bh[nt] = __builtin_bit_cast(bf16x8, q4[(ks * 4 + lg) * 64 + nt * 16 + l15]);
        #pragma unroll
        for (int rt = 0; rt < 2; ++rt) {
            bf16x8 ah = __builtin_bit_cast(bf16x8,
                mp4[((2 * w + rt) * 4 + ks) * 64 + lane]);
            #pragma unroll
            for (int nt = 0; nt < 4; ++nt)
                acc2[rt][nt] = __builtin_amdgcn_mfma_f32_16x16x32_bf16(ah, bh[nt], acc2[rt][nt], 0, 0, 0);
        }
    }
    float* ob = out + (size_t)b * (128 * 4096) + tile * 64;
    #pragma unroll
    for (int rt = 0; rt < 2; ++rt)
        #pragma unroll
        for (int r = 0; r < 4; ++r) {
            int ch = w * 32 + rt * 16 + lg * 4 + r;
            float bo = b_out[ch];            // L2-hot, 128 floats total
            #pragma unroll
            for (int nt = 0; nt < 4; ++nt)
                ob[(size_t)ch * 4096 + nt * 16 + l15] = acc2[rt][nt][r] + bo;
        }
}

extern "C" void kernel_launch(void* const* d_in, const int* in_sizes, int n_in,
                              void* d_out, int out_size, void* d_ws, size_t ws_size,
                              hipStream_t stream) {
    const float* x     = (const float*)d_in[0];
    const float* w_qkv = (const float*)d_in[1];
    const float* wA_q  = (const float*)d_in[2];
    const float* bA_q  = (const float*)d_in[3];
    const float* wB_q  = (const float*)d_in[4];
    const float* bB_q  = (const float*)d_in[5];
    const float* wA_k  = (const float*)d_in[6];
    const float* bA_k  = (const float*)d_in[7];
    const float* wB_k  = (const float*)d_in[8];
    const float* bB_k  = (const float*)d_in[9];
    const float* wA_v  = (const float*)d_in[10];
    const float* bA_v  = (const float*)d_in[11];
    const float* wB_v  = (const float*)d_in[12];
    const float* bB_v  = (const float*)d_in[13];
    const float* w_out = (const float*)d_in[14];
    const float* b_out = (const float*)d_in[15];
    float* out = (float*)d_out;

    float* ws = (float*)d_ws;
    float*    beff  = ws;                             // 384 f
    unsigned* part  = (unsigned*)(ws + 384);          // 16*4*64*544 = 2228224 u32
    float*    part2 = ws + 384 + 2228224;             // 16*4*16*1056 = 1081344 f
    unsigned* wq    = (unsigned*)(ws + 3309952);      // 8192 u32
    unsigned* wkv   = (unsigned*)(ws + 3318144);      // 16384 u32
    unsigned* mpk   = (unsigned*)(ws + 3334528);      // 131072 u32
    uint4*    qs    = (uint4*)(ws + 3465600);         // 1048576 uint4 (16 MB)

    prep_kernel<<<97, 256, 0, stream>>>(w_qkv,
        wA_q, bA_q, wB_q, bB_q, wA_k, bA_k, wB_k, bB_k, wA_v, bA_v, wB_v, bB_v,
        wq, wkv, beff);
    ctx_fused_kernel<<<dim3(NCHUNK, 16), 256, 0, stream>>>(x, wq, wkv, beff,
        part, qs);
    combine_a_kernel<<<dim3(4, 16, 16), 256, 0, stream>>>(part, part2);
    combine_b_kernel<<<dim3(4, 16), 256, 0, stream>>>(part2, w_out, beff, mpk);
    out_kernel<<<dim3(64, 16), 256, 0, stream>>>(qs, mpk, b_out, out);
}

// Round 24
// 50.509 us; speedup vs baseline: 1.1488x; 1.0017x over previous
//
#include <hip/hip_runtime.h>

// loraLinearAttention on MI355X — FINAL (R23 configuration, 50.6us measured,
// absmax 7.45e-9). Journey: 221us (R3 fp32 baseline) -> 50.6us via: LoRA
// fold into effective weights; linear attention collapsed to per-(b,h) 32x32
// ctx + per-batch M; all GEMMs on bf16 MFMA (single-bf16 weights/activations
// everywhere error budget allows — outputs ~1e-5 abs, so bf16 rel error
// lands at ~1e-8 abs); k-bias dropped exactly (exp(bk) cancels in ctx/l);
// v-bias folded into combine; q fused into ctx (x read once); bf16-packed
// partials; 2-stage combine; read-once qs in out.

typedef float f32x4 __attribute__((ext_vector_type(4)));
typedef short bf16x8 __attribute__((ext_vector_type(8)));

#define SCALING 0.25f
#define SCALE   0.17677669529663687f   /* 32^-0.5 */
#define NCHUNK  64                     /* 64-px chunks per (b,h) */
#define PSTRIDE 544                    /* u32 per (b,h,chunk): 512 ctx pairs + 32 l */

__device__ __forceinline__ unsigned short f2bf_rn(float x) {
    union { float f; unsigned u; } v; v.f = x;
    unsigned r = v.u + 0x7FFFu + ((v.u >> 16) & 1u);
    return (unsigned short)(r >> 16);
}
__device__ __forceinline__ float bf2f(unsigned h16) {
    union { unsigned u; float f; } v; v.u = h16 << 16;
    return v.f;
}
__device__ __forceinline__ unsigned pack2(float a, float b) {
    return (unsigned)f2bf_rn(a) | ((unsigned)f2bf_rn(b) << 16);
}

__device__ __forceinline__ float weff(
    const float* __restrict__ w_qkv, const float* __restrict__ wA,
    const float* __restrict__ wB, int m, int o, int c)
{
    float s = w_qkv[(m * 128 + o) * 128 + c];
    #pragma unroll
    for (int r = 0; r < 4; ++r)
        s += SCALING * wB[o * 4 + r] * wA[r * 128 + c];
    return s;
}

// grid 97 x 256. tid<8192: Wq A-frag single-bf16 pairs; 8192..24575: Wkv.
// Block 96: beff (q bias for softmax, v bias for combine; k bias dropped).
__global__ __launch_bounds__(256) void prep_kernel(
    const float* __restrict__ w_qkv,
    const float* __restrict__ wA_q, const float* __restrict__ bA_q,
    const float* __restrict__ wB_q, const float* __restrict__ bB_q,
    const float* __restrict__ wA_k, const float* __restrict__ bA_k,
    const float* __restrict__ wB_k, const float* __restrict__ bB_k,
    const float* __restrict__ wA_v, const float* __restrict__ bA_v,
    const float* __restrict__ wB_v, const float* __restrict__ bB_v,
    unsigned* __restrict__ wq, unsigned* __restrict__ wkv,
    float* __restrict__ beff)
{
    const int t = threadIdx.x;
    if (blockIdx.x == 96) {
        for (int ii = t; ii < 384; ii += 256) {
            int mm = ii >> 7, oo = ii & 127;
            const float* wBm = (mm == 0) ? wB_q : (mm == 1) ? wB_k : wB_v;
            const float* bAm = (mm == 0) ? bA_q : (mm == 1) ? bA_k : bA_v;
            const float* bBm = (mm == 0) ? bB_q : (mm == 1) ? bB_k : bB_v;
            float bb = bBm[oo];
            #pragma unroll
            for (int r = 0; r < 4; ++r) bb += wBm[oo * 4 + r] * bAm[r];
            beff[ii] = SCALING * bb;
        }
        return;
    }
    int tid = blockIdx.x * 256 + t;
    if (tid < 8192) {                       // Wq A-frag, single bf16
        int fp = tid;
        int f = fp * 2;
        int i = f & 7;
        int l = (f >> 3) & 63;
        int rgks = f >> 9;                  // 0..31
        int rg = rgks >> 2, ks = rgks & 3;  // rg 0..7
        int o = rg * 16 + (l & 15);         // q row 0..127
        int c = ks * 32 + ((l >> 4) & 3) * 8 + i;
        wq[fp] = pack2(weff(w_qkv, wA_q, wB_q, 0, o, c),
                       weff(w_qkv, wA_q, wB_q, 0, o, c + 1));
    } else {                                // Wkv A-frag, single bf16
        int fp = tid - 8192;
        int f = fp * 2;
        int i = f & 7;
        int l = (f >> 3) & 63;
        int rtks = f >> 9;                  // 0..63
        int rt = rtks >> 2, ks = rtks & 3;  // rt 0..15
        int row = rt * 16 + (l & 15);       // kv row 0..255
        int c = ks * 32 + ((l >> 4) & 3) * 8 + i;
        int m = 1 + (row >> 7), o = row & 127;
        const float* wA = (m == 1) ? wA_k : wA_v;
        const float* wB = (m == 1) ? wB_k : wB_v;
        wkv[fp] = pack2(weff(w_qkv, wA, wB, m, o, c),
                        weff(w_qkv, wA, wB, m, o, c + 1));
    }
}

// grid (chunk=64, b=16) = 1024 blocks, 256 threads (4 waves), 36.9KB LDS.
// Wave w, sequentially: stage x quarter -> q head w (32 MFMA, softmax,
// qs->global) -> kv rows 64w (32 MFMA, exp for w<2, early pack) -> barrier
// -> kv->LDS -> barrier -> ctx P.V^T + l -> part (bf16-packed pairs).
__global__ __launch_bounds__(256) void ctx_fused_kernel(
    const float* __restrict__ x, const unsigned* __restrict__ wq,
    const unsigned* __restrict__ wkv, const float* __restrict__ beff,
    unsigned* __restrict__ part, uint4* __restrict__ qs)
{
    __shared__ __align__(16) char smem[36864];
    uint4* xs = (uint4*)smem;                     // 16 KB (dead after GEMM1s)
    unsigned short* kv = (unsigned short*)smem;   // [256][72] bf16
    const int t = threadIdx.x;
    const int lane = t & 63;
    const int w = __builtin_amdgcn_readfirstlane(t >> 6);  // 0..3
    const int chunk = blockIdx.x, b = blockIdx.y;
    const int lg = lane >> 4, l15 = lane & 15;
    const float* xb = x + (size_t)b * (128 * 4096);
    const int n0 = chunk * 64;
    const uint4* wq4 = (const uint4*)wq;
    const uint4* wkv4 = (const uint4*)wkv;

    // stage x single-bf16 B-frags: wave w -> channel groups p*4+w (p=0..3),
    // issued as two 16-load groups for deeper in-flight load queues.
    #pragma unroll
    for (int pp = 0; pp < 2; ++pp) {
        float v[16];
        #pragma unroll
        for (int g2 = 0; g2 < 2; ++g2) {
            int g = (pp * 2 + g2) * 4 + w;
            #pragma unroll
            for (int j = 0; j < 8; ++j)
                v[g2 * 8 + j] = xb[(size_t)(g * 8 + j) * 4096 + n0 + lane];
        }
        #pragma unroll
        for (int g2 = 0; g2 < 2; ++g2) {
            int g = (pp * 2 + g2) * 4 + w;
            xs[g * 64 + lane] = make_uint4(
                pack2(v[g2*8+0], v[g2*8+1]), pack2(v[g2*8+2], v[g2*8+3]),
                pack2(v[g2*8+4], v[g2*8+5]), pack2(v[g2*8+6], v[g2*8+7]));
        }
    }
    __syncthreads();

    // ===== q: head w, rows 32w+16rt+lg*4+r =====
    {
        f32x4 acc[2][4];
        #pragma unroll
        for (int rt = 0; rt < 2; ++rt)
            #pragma unroll
            for (int nt = 0; nt < 4; ++nt)
                acc[rt][nt] = (f32x4){0.f, 0.f, 0.f, 0.f};
        #pragma unroll
        for (int ks = 0; ks < 4; ++ks) {
            bf16x8 bh[4];
            #pragma unroll
            for (int nt = 0; nt < 4; ++nt)
                bh[nt] = __builtin_bit_cast(bf16x8, xs[(ks * 4 + lg) * 64 + nt * 16 + l15]);
            #pragma unroll
            for (int rt = 0; rt < 2; ++rt) {
                bf16x8 ah = __builtin_bit_cast(bf16x8,
                    wq4[((2 * w + rt) * 4 + ks) * 64 + lane]);
                #pragma unroll
                for (int nt = 0; nt < 4; ++nt)
                    acc[rt][nt] = __builtin_amdgcn_mfma_f32_16x16x32_bf16(ah, bh[nt], acc[rt][nt], 0, 0, 0);
            }
        }
        float bq[2][4];
        #pragma unroll
        for (int rt = 0; rt < 2; ++rt)
            #pragma unroll
            for (int r = 0; r < 4; ++r)
                bq[rt][r] = beff[w * 32 + rt * 16 + lg * 4 + r];
        #pragma unroll
        for (int nt = 0; nt < 4; ++nt) {
            float m = -1e30f;
            #pragma unroll
            for (int rt = 0; rt < 2; ++rt)
                #pragma unroll
                for (int r = 0; r < 4; ++r) {
                    float q = acc[rt][nt][r] + bq[rt][r];
                    acc[rt][nt][r] = q;
                    m = fmaxf(m, q);
                }
            m = fmaxf(m, __shfl_xor(m, 16));
            m = fmaxf(m, __shfl_xor(m, 32));
            float s = 0.f;
            #pragma unroll
            for (int rt = 0; rt < 2; ++rt)
                #pragma unroll
                for (int r = 0; r < 4; ++r) {
                    float e = __expf(acc[rt][nt][r] - m);
                    acc[rt][nt][r] = e;
                    s += e;
                }
            s += __shfl_xor(s, 16);
            s += __shfl_xor(s, 32);
            float inv = 1.0f / s;
            #pragma unroll
            for (int rt = 0; rt < 2; ++rt)
                #pragma unroll
                for (int r = 0; r < 4; ++r)
                    acc[rt][nt][r] *= inv;
        }
        uint2* q2g = (uint2*)(qs + ((size_t)b * 64 + chunk) * 1024);
        int half = (lg & 1);
        #pragma unroll
        for (int rt = 0; rt < 2; ++rt) {
            int kb = rt * 2 + (lg >> 1);
            #pragma unroll
            for (int nt = 0; nt < 4; ++nt) {
                int idx = ((w * 4 + kb) * 64 + nt * 16 + l15) * 2 + half;
                q2g[idx] = make_uint2(pack2(acc[rt][nt][0], acc[rt][nt][1]),
                                      pack2(acc[rt][nt][2], acc[rt][nt][3]));
            }
        }
    }

    // ===== kv: rows 64w..+63; exp for K (w<2); early bf16 pack =====
    unsigned pk[4][8];
    #pragma unroll
    for (int rt = 0; rt < 4; ++rt) {
        f32x4 acc[4];
        #pragma unroll
        for (int nt = 0; nt < 4; ++nt) acc[nt] = (f32x4){0.f, 0.f, 0.f, 0.f};
        #pragma unroll
        for (int ks = 0; ks < 4; ++ks) {
            bf16x8 ah = __builtin_bit_cast(bf16x8,
                wkv4[((4 * w + rt) * 4 + ks) * 64 + lane]);
            #pragma unroll
            for (int nt = 0; nt < 4; ++nt) {
                bf16x8 bh = __builtin_bit_cast(bf16x8,
                    xs[(ks * 4 + lg) * 64 + nt * 16 + l15]);
                acc[nt] = __builtin_amdgcn_mfma_f32_16x16x32_bf16(ah, bh, acc[nt], 0, 0, 0);
            }
        }
        #pragma unroll
        for (int nt = 0; nt < 4; ++nt) {
            float v0 = acc[nt][0], v1 = acc[nt][1];
            float v2 = acc[nt][2], v3 = acc[nt][3];
            if (w < 2) {                 // K waves: exp in regs
                v0 = __expf(v0); v1 = __expf(v1);
                v2 = __expf(v2); v3 = __expf(v3);
            }
            pk[rt][nt * 2]     = pack2(v0, v1);
            pk[rt][nt * 2 + 1] = pack2(v2, v3);
        }
    }
    __syncthreads();                     // all xs reads done (kv overwrites)
    #pragma unroll
    for (int rt = 0; rt < 4; ++rt)
        #pragma unroll
        for (int nt = 0; nt < 4; ++nt)
            #pragma unroll
            for (int rr = 0; rr < 2; ++rr) {
                unsigned u = pk[rt][nt * 2 + rr];
                int row0 = 64 * w + 16 * rt + lg * 4 + rr * 2;
                int px = nt * 16 + l15;
                kv[row0 * 72 + px] = (unsigned short)u;
                kv[(row0 + 1) * 72 + px] = (unsigned short)(u >> 16);
            }
    __syncthreads();

    // ===== ctx: head w (P rows 32w.., V rows 128+32w..) + l =====
    bf16x8 ones;
    #pragma unroll
    for (int i = 0; i < 8; ++i) ones[i] = (short)0x3F80;
    f32x4 ctx_acc[2][2];
    f32x4 l_acc[2];
    #pragma unroll
    for (int rt = 0; rt < 2; ++rt) {
        l_acc[rt] = (f32x4){0.f, 0.f, 0.f, 0.f};
        #pragma unroll
        for (int et = 0; et < 2; ++et)
            ctx_acc[rt][et] = (f32x4){0.f, 0.f, 0.f, 0.f};
    }
    #pragma unroll
    for (int ks2 = 0; ks2 < 2; ++ks2) {
        int pxb = ks2 * 32 + lg * 8;
        bf16x8 ph[2], vh[2];
        #pragma unroll
        for (int rt = 0; rt < 2; ++rt)
            ph[rt] = __builtin_bit_cast(bf16x8, *(const uint4*)&kv[(32 * w + 16 * rt + l15) * 72 + pxb]);
        #pragma unroll
        for (int et = 0; et < 2; ++et)
            vh[et] = __builtin_bit_cast(bf16x8, *(const uint4*)&kv[(128 + 32 * w + 16 * et + l15) * 72 + pxb]);
        #pragma unroll
        for (int rt = 0; rt < 2; ++rt) {
            #pragma unroll
            for (int et = 0; et < 2; ++et)
                ctx_acc[rt][et] = __builtin_amdgcn_mfma_f32_16x16x32_bf16(ph[rt], vh[et], ctx_acc[rt][et], 0, 0, 0);
            l_acc[rt] = __builtin_amdgcn_mfma_f32_16x16x32_bf16(ph[rt], ones, l_acc[rt], 0, 0, 0);
        }
    }
    // part write, bf16-packed: u32[d*16+l15] = pack2(ctx[d][l15], ctx[d][16+l15])
    unsigned* pout = part + (size_t)((b * 4 + w) * NCHUNK + chunk) * PSTRIDE;
    #pragma unroll
    for (int rt = 0; rt < 2; ++rt) {
        #pragma unroll
        for (int r = 0; r < 4; ++r) {
            int d = 16 * rt + lg * 4 + r;
            pout[d * 16 + l15] = pack2(ctx_acc[rt][0][r], ctx_acc[rt][1][r]);
        }
        if (l15 == 0)
            #pragma unroll
            for (int r = 0; r < 4; ++r)
                pout[512 + 16 * rt + lg * 4 + r] = __float_as_uint(l_acc[rt][r]);
    }
}

// grid (4 heads, 16 b, 16 groups), 256 threads: partial-reduce 4 chunks
// (bf16 unpack -> f32 sums; part2 f32 layout [d*32+e] + l @1024).
__global__ __launch_bounds__(256) void combine_a_kernel(
    const unsigned* __restrict__ part, float* __restrict__ part2)
{
    const int t = threadIdx.x;
    const int h = blockIdx.x, b = blockIdx.y, g = blockIdx.z;
    const unsigned* pb = part + (size_t)((b * 4 + h) * NCHUNK + g * 4) * PSTRIDE;
    float slo[2] = {0.f, 0.f}, shi[2] = {0.f, 0.f};
    #pragma unroll
    for (int ch = 0; ch < 4; ++ch) {
        #pragma unroll
        for (int i = 0; i < 2; ++i) {
            unsigned u = pb[(size_t)ch * PSTRIDE + i * 256 + t];
            slo[i] += bf2f(u & 0xFFFFu);
            shi[i] += bf2f(u >> 16);
        }
    }
    float* po = part2 + (size_t)(((b * 4 + h) * 16) + g) * 1056;
    #pragma unroll
    for (int i = 0; i < 2; ++i) {
        int p = i * 256 + t;
        int d = p >> 4, e = p & 15;
        po[d * 32 + e] = slo[i];
        po[d * 32 + 16 + e] = shi[i];
    }
    if (t < 32) {
        float l = 0.f;
        #pragma unroll
        for (int ch = 0; ch < 4; ++ch)
            l += __uint_as_float(pb[(size_t)ch * PSTRIDE + 512 + t]);
        po[1024 + t] = l;
    }
}

// grid (4 heads, 16 batches), 256 threads: final reduce (16 partials) +
// normalize + M-pack (single bf16).
__global__ __launch_bounds__(256) void combine_b_kernel(
    const float* __restrict__ part2, const float* __restrict__ w_out,
    const float* __restrict__ beff, unsigned* __restrict__ mpk)
{
    __shared__ float ctx_s[32 * 33];
    __shared__ float w_s[128 * 33];
    __shared__ float linv_s[32];
    __shared__ float bv_s[32];
    const int t = threadIdx.x;
    const int h = blockIdx.x, b = blockIdx.y;
    const float* pb = part2 + (size_t)((b * 4 + h) * 16) * 1056;

    if (t < 32) {
        float l = 0.f;
        #pragma unroll
        for (int p = 0; p < 16; ++p) l += pb[(size_t)p * 1056 + 1024 + t];
        linv_s[t] = 1.0f / (l * 4096.0f);
        bv_s[t] = beff[256 + h * 32 + t];
    }
    #pragma unroll
    for (int i = 0; i < 16; ++i) {
        int idx = i * 256 + t;
        int e = idx & 31, o = idx >> 5;
        w_s[o * 33 + e] = w_out[o * 128 + h * 32 + e];
    }
    float csum[4] = {0.f, 0.f, 0.f, 0.f};
    #pragma unroll
    for (int p = 0; p < 16; ++p) {
        #pragma unroll
        for (int i = 0; i < 4; ++i)
            csum[i] += pb[(size_t)p * 1056 + i * 256 + t];
    }
    __syncthreads();
    #pragma unroll
    for (int i = 0; i < 4; ++i) {
        int idx = i * 256 + t;
        int d = idx >> 5, e = idx & 31;
        ctx_s[d * 33 + e] = csum[i] * linv_s[d] + bv_s[e] * (1.0f / 4096.0f);
    }
    __syncthreads();
    #pragma unroll 1
    for (int it = 0; it < 8; ++it) {
        int p = it * 256 + t;
        int rt = p >> 8;
        int l = (p >> 2) & 63;
        int ip = p & 3;
        int o = rt * 16 + (l & 15);
        int d0 = (l >> 4) * 8 + 2 * ip;
        float v0 = 0.f, v1 = 0.f;
        #pragma unroll
        for (int e = 0; e < 32; ++e) {
            float wv = w_s[o * 33 + e];
            v0 = fmaf(wv, ctx_s[d0 * 33 + e], v0);
            v1 = fmaf(wv, ctx_s[(d0 + 1) * 33 + e], v1);
        }
        size_t fp = (size_t)b * 8192 + ((rt * 4 + h) * 64 + l) * 4 + ip;
        mpk[fp] = pack2(v0 * SCALE, v1 * SCALE);
    }
}

// grid (tile=64, b=16) = 1024 blocks, 256 threads. GEMM2: out = M.qs
// + b_out, 64 px/block, M single-bf16 (32 MFMA). Bias from global (L2-hot),
// no LDS, no barrier.
__global__ __launch_bounds__(256) void out_kernel(
    const uint4* __restrict__ qs, const unsigned* __restrict__ mpk,
    const float* __restrict__ b_out, float* __restrict__ out)
{
    const int t = threadIdx.x;
    const int tile = blockIdx.x, b = blockIdx.y;
    const int lane = t & 63;
    const int w = __builtin_amdgcn_readfirstlane(t >> 6);
    const int lg = lane >> 4, l15 = lane & 15;

    const uint4* q4 = qs + ((size_t)b * 64 + tile) * 1024;
    const uint4* mp4 = (const uint4*)(mpk + (size_t)b * 8192);
    f32x4 acc2[2][4];
    #pragma unroll
    for (int rt = 0; rt < 2; ++rt)
        #pragma unroll
        for (int nt = 0; nt < 4; ++nt)
            acc2[rt][nt] = (f32x4){0.f, 0.f, 0.f, 0.f};
    #pragma unroll
    for (int ks = 0; ks < 4; ++ks) {
        bf16x8 bh[4];
        #pragma unroll
        for (int nt = 0; nt < 4; ++nt)
            bh[nt] = __builtin_bit_cast(bf16x8, q4[(ks * 4 + lg) * 64 + nt * 16 + l15]);
        #pragma unroll
        for (int rt = 0; rt < 2; ++rt) {
            bf16x8 ah = __builtin_bit_cast(bf16x8,
                mp4[((2 * w + rt) * 4 + ks) * 64 + lane]);
            #pragma unroll
            for (int nt = 0; nt < 4; ++nt)
                acc2[rt][nt] = __builtin_amdgcn_mfma_f32_16x16x32_bf16(ah, bh[nt], acc2[rt][nt], 0, 0, 0);
        }
    }
    float* ob = out + (size_t)b * (128 * 4096) + tile * 64;
    #pragma unroll
    for (int rt = 0; rt < 2; ++rt)
        #pragma unroll
        for (int r = 0; r < 4; ++r) {
            int ch = w * 32 + rt * 16 + lg * 4 + r;
            float bo = b_out[ch];            // L2-hot, 128 floats total
            #pragma unroll
            for (int nt = 0; nt < 4; ++nt)
                ob[(size_t)ch * 4096 + nt * 16 + l15] = acc2[rt][nt][r] + bo;
        }
}

extern "C" void kernel_launch(void* const* d_in, const int* in_sizes, int n_in,
                              void* d_out, int out_size, void* d_ws, size_t ws_size,
                              hipStream_t stream) {
    const float* x     = (const float*)d_in[0];
    const float* w_qkv = (const float*)d_in[1];
    const float* wA_q  = (const float*)d_in[2];
    const float* bA_q  = (const float*)d_in[3];
    const float* wB_q  = (const float*)d_in[4];
    const float* bB_q  = (const float*)d_in[5];
    const float* wA_k  = (const float*)d_in[6];
    const float* bA_k  = (const float*)d_in[7];
    const float* wB_k  = (const float*)d_in[8];
    const float* bB_k  = (const float*)d_in[9];
    const float* wA_v  = (const float*)d_in[10];
    const float* bA_v  = (const float*)d_in[11];
    const float* wB_v  = (const float*)d_in[12];
    const float* bB_v  = (const float*)d_in[13];
    const float* w_out = (const float*)d_in[14];
    const float* b_out = (const float*)d_in[15];
    float* out = (float*)d_out;

    float* ws = (float*)d_ws;
    float*    beff  = ws;                             // 384 f
    unsigned* part  = (unsigned*)(ws + 384);          // 16*4*64*544 = 2228224 u32
    float*    part2 = ws + 384 + 2228224;             // 16*4*16*1056 = 1081344 f
    unsigned* wq    = (unsigned*)(ws + 3309952);      // 8192 u32
    unsigned* wkv   = (unsigned*)(ws + 3318144);      // 16384 u32
    unsigned* mpk   = (unsigned*)(ws + 3334528);      // 131072 u32
    uint4*    qs    = (uint4*)(ws + 3465600);         // 1048576 uint4 (16 MB)

    prep_kernel<<<97, 256, 0, stream>>>(w_qkv,
        wA_q, bA_q, wB_q, bB_q, wA_k, bA_k, wB_k, bB_k, wA_v, bA_v, wB_v, bB_v,
        wq, wkv, beff);
    ctx_fused_kernel<<<dim3(NCHUNK, 16), 256, 0, stream>>>(x, wq, wkv, beff,
        part, qs);
    combine_a_kernel<<<dim3(4, 16, 16), 256, 0, stream>>>(part, part2);
    combine_b_kernel<<<dim3(4, 16), 256, 0, stream>>>(part2, w_out, beff, mpk);
    out_kernel<<<dim3(64, 16), 256, 0, stream>>>(qs, mpk, b_out, out);
}